// Round 7
// baseline (894.643 us; speedup 1.0000x reference)
//
#include <hip/hip_runtime.h>
#include <hip/hip_bf16.h>
#include <hip/hip_fp16.h>

typedef __hip_bfloat16 bf16;
typedef unsigned short ushort_t;
typedef unsigned short us8 __attribute__((ext_vector_type(8)));
typedef _Float16 half8 __attribute__((ext_vector_type(8)));
typedef float f32x4 __attribute__((ext_vector_type(4)));

#define NEG 0.2f
#define LNEPS 1e-5f
#define BWD 512                 // CSR bucket width (nodes)

__device__ __forceinline__ int plaus(unsigned int lo){
    lo &= 0x7FFFu;
    if (lo == 0) return 1;
    unsigned int ex = (lo >> 7) & 0xFF;
    return (ex >= 100 && ex <= 140) ? 1 : 0;
}

__device__ __forceinline__ float decode_slot(const ushort_t* s, long long i, int fl){
    long long base = i << fl;
    unsigned int hi = s[base + fl];
    unsigned int lo = s[base];
    unsigned int bits = (hi << 16) | (lo * (unsigned int)fl);
    return __uint_as_float(bits);
}

// order-preserving float<->uint encoding for atomicMax on floats (incl. negatives)
__device__ __forceinline__ unsigned encf(float f){
    int b = __float_as_int(f);
    return (b >= 0) ? ((unsigned)b | 0x80000000u) : (unsigned)(~b);
}
__device__ __forceinline__ float decf(unsigned k){
    return (k & 0x80000000u) ? __uint_as_float(k & 0x7FFFFFFFu)
                             : __uint_as_float(~k);
}

// ---------- per-tensor dtype flags ----------
__global__ void k_detect(const void* t0, const void* t1, const void* t2, const void* t3,
                         const void* t4, const void* t5, const void* t6, const void* t7,
                         const void* t8, const void* lng, int* flags){
    int t = threadIdx.x;
    if (blockIdx.x != 0) return;
    if (t < 9){
        const void* ptrs[9] = {t0,t1,t2,t3,t4,t5,t6,t7,t8};
        const ushort_t* w = (const ushort_t*)ptrs[t];
        int all_bf = 1;
        for (int i = 0; i < 16; i++) all_bf &= plaus((unsigned int)w[i]);
        flags[t] = all_bf ? 0 : 1;
    } else if (t == 9){
        const ushort_t* w = (const ushort_t*)lng;
        flags[9] = (w[0] == 0x3F80u) ? 0 : 1;
    }
}

// ---------- stage params ----------
#define P_TOTAL 56577
__global__ void k_convert(const void* p0, const void* p1, const void* p2, const void* p3,
        const void* p4, const void* p5, const void* p6, const void* p7, const void* p8,
        const void* p9, const void* p10, const void* p11, const void* p12, const void* p13,
        const void* p14, const int* flags, float* P){
    int idx = blockIdx.x*blockDim.x + threadIdx.x;
    if (idx >= P_TOTAL) return;
    const int sizes[15] = {4096,64,12288,12288,192,192,192,24576,192,192,192,2048,32,32,1};
    const int fidx[15]  = {1,  -1,  2,    3,    4,  5,  -1, 6,    -1, 9,  -1, 7,   -1,8, -1};
    const void* ptrs[15] = {p0,p1,p2,p3,p4,p5,p6,p7,p8,p9,p10,p11,p12,p13,p14};
    int s = 0, base = 0;
    while (idx - base >= sizes[s]){ base += sizes[s]; s++; }
    int li = idx - base;
    int fi = fidx[s];
    int fl = (fi >= 0) ? flags[fi] : 0;
    P[idx] = decode_slot((const ushort_t*)ptrs[s], li, fl);
}

// ---------- bucketed CSR build ----------
__global__ __launch_bounds__(1024) void kb_hist(const int* __restrict__ row,
        const int* __restrict__ col, int* __restrict__ bcnt, int NBK, int E){
    __shared__ int lh[512];
    int t = threadIdx.x;
    for (int i = t; i < 2*NBK; i += 1024) lh[i] = 0;
    __syncthreads();
    for (long long e = (long long)blockIdx.x*1024 + t; e < E; e += (long long)gridDim.x*1024){
        atomicAdd(&lh[row[e] >> 9], 1);
        atomicAdd(&lh[NBK + (col[e] >> 9)], 1);
    }
    __syncthreads();
    for (int i = t; i < 2*NBK; i += 1024){
        int v = lh[i];
        if (v) atomicAdd(&bcnt[i], v);
    }
}

__global__ __launch_bounds__(256) void kb_scan(const int* __restrict__ bcnt,
        int* __restrict__ bptr_r, int* __restrict__ bptr_c,
        int* __restrict__ bcur_r, int* __restrict__ bcur_c, int NBK, int E){
    __shared__ int sh[256];
    int side = blockIdx.x;
    const int* c = bcnt + side*NBK;
    int* bp = side ? bptr_c : bptr_r;
    int* bc = side ? bcur_c : bcur_r;
    int t = threadIdx.x;
    int v = (t < NBK) ? c[t] : 0;
    sh[t] = v; __syncthreads();
    for (int off = 1; off < 256; off <<= 1){
        int add = (t >= off) ? sh[t-off] : 0;
        __syncthreads();
        sh[t] += add;
        __syncthreads();
    }
    if (t < NBK){ int e = sh[t] - v; bp[t] = e; bc[t] = e; }
    if (t == 0) bp[NBK] = E;
}

__global__ __launch_bounds__(1024) void kb_bin(const int* __restrict__ key,
        const int* __restrict__ pay, int* __restrict__ bcur,
        uint2* __restrict__ stage, int NBK, int E){
    __shared__ int lh[256], lbase[256];
    int t = threadIdx.x;
    for (long long tile = (long long)blockIdx.x*1024; tile < E; tile += (long long)gridDim.x*1024){
        for (int i = t; i < NBK; i += 1024) lh[i] = 0;
        __syncthreads();
        int e = (int)tile + t;
        int k = 0, p = 0, b = -1, rank = 0;
        if (e < E){
            k = key[e]; p = pay[e]; b = k >> 9;
            rank = atomicAdd(&lh[b], 1);
        }
        __syncthreads();
        for (int i = t; i < NBK; i += 1024){
            int c = lh[i];
            lbase[i] = c ? atomicAdd(&bcur[i], c) : 0;
        }
        __syncthreads();
        if (b >= 0) stage[lbase[b] + rank] = make_uint2((unsigned)k, (unsigned)p);
        __syncthreads();
    }
}

__global__ __launch_bounds__(1024) void kb_place(const uint2* __restrict__ stage,
        const int* __restrict__ bptr, int* __restrict__ ptr, int* __restrict__ outarr,
        float* __restrict__ dinv, int wantdinv, int N, int E){
    __shared__ int lcnt[BWD], lsc[BWD], lcur[BWD];
    int b = blockIdx.x;
    int s = bptr[b], e = bptr[b+1];
    int nbase = b << 9;
    int t = threadIdx.x;
    if (t < BWD) lcnt[t] = 0;
    __syncthreads();
    for (int i = s + t; i < e; i += 1024)
        atomicAdd(&lcnt[stage[i].x - nbase], 1);
    __syncthreads();
    if (t < BWD) lsc[t] = lcnt[t];
    __syncthreads();
    for (int off = 1; off < BWD; off <<= 1){
        int add = (t >= off && t < BWD) ? lsc[t-off] : 0;
        __syncthreads();
        if (t < BWD) lsc[t] += add;
        __syncthreads();
    }
    if (t < BWD){
        int node = nbase + t;
        int excl = lsc[t] - lcnt[t];
        lcur[t] = excl;
        if (node < N){
            ptr[node] = s + excl;
            if (wantdinv) dinv[node] = lcnt[t] > 0 ? rsqrtf((float)lcnt[t]) : 0.f;
        }
    }
    if (b == 0 && t == 0) ptr[N] = E;
    __syncthreads();
    for (int i = s + t; i < e; i += 1024){
        uint2 rec = stage[i];
        int pos = s + atomicAdd(&lcur[rec.x - nbase], 1);
        outarr[pos] = (int)rec.y;
    }
}

// ---------- precompute fused weights ----------
__global__ void k_prew(const float* __restrict__ fus_W, const float* __restrict__ e8_W,
                       const float* __restrict__ gat_b, const float* __restrict__ fus_b,
                       float* __restrict__ W1c, float* __restrict__ b2c){
    int t = blockIdx.x*blockDim.x + threadIdx.x;
    if (t < 3*4096){
        int i = t >> 12, jq = t & 4095, j = jq >> 6, q = jq & 63;
        const float* fw = fus_W + (size_t)i*64*128 + (size_t)j*128;
        const float* ew = e8_W + (size_t)i*4096;
        float acc = 0.f;
        for (int p = 0; p < 64; p++) acc += fw[p] * ew[p*64+q];
        W1c[t] = acc;
    }
    if (t < 3*64){
        int i = t >> 6, j = t & 63;
        const float* fw = fus_W + (size_t)i*64*128 + (size_t)j*128 + 64;
        float acc = fus_b[i*64+j];
        for (int p = 0; p < 64; p++) acc += gat_b[i*64+p] * fw[p];
        b2c[t] = acc;
    }
}

// ---------- pre-swizzle fusion weights into MFMA B-fragment order (fp16) ----------
__global__ void k_prewB(const float* __restrict__ W1c, const float* __restrict__ fus_W,
                        _Float16* __restrict__ Bfrag){
    int idx = blockIdx.x*blockDim.x + threadIdx.x;
    if (idx >= 3*8192) return;
    int i = idx / 8192; int rem = idx & 8191;
    int j = rem & 7, lane = (rem >> 3) & 63, kk = (rem >> 9) & 3, t = rem >> 11;
    int k = kk*32 + (lane >> 4)*8 + j;
    int n = t*16 + (lane & 15);
    float v = (k < 64) ? W1c[i*4096 + n*64 + k]
                       : fus_W[(size_t)i*8192 + n*128 + 64 + (k - 64)];
    Bfrag[idx] = (_Float16)v;
}

// ---------- pre-swizzle gat_W into B-frag order: 5 t-tiles x 2 kk-steps ----------
// t=0..3: G columns. t=4: columns 0..7 = att-folded projections
// (col 2h = gat_W[:,h-block]@att_src[h], col 2h+1 = @att_dst[h]), cols 8..15 zero.
__global__ void k_prewBg(const float* __restrict__ gat_W, const float* __restrict__ att_src,
                         const float* __restrict__ att_dst, _Float16* __restrict__ Bg){
    int idx = blockIdx.x*blockDim.x + threadIdx.x;
    if (idx >= 3*5120) return;
    int i = idx / 5120; int rem = idx % 5120;
    int j = rem & 7, lane = (rem >> 3) & 63, kk = (rem >> 9) & 1, t = rem >> 10;
    int k = kk*32 + (lane >> 4)*8 + j;
    int nn = lane & 15;
    float v;
    if (t < 4){
        v = gat_W[(size_t)i*4096 + k*64 + (t*16 + nn)];
    } else if (nn < 8){
        int hx = nn >> 1;
        const float* att = (nn & 1) ? att_dst : att_src;
        float acc = 0.f;
        for (int c = 0; c < 16; c++)
            acc += gat_W[(size_t)i*4096 + k*64 + hx*16 + c] * att[i*64 + hx*16 + c];
        v = acc;
    } else {
        v = 0.f;
    }
    Bg[idx] = (_Float16)v;
}

// ---------- embedding: h16 + ht16 = dinv*h (fp32 h mirror dropped) ----------
__global__ __launch_bounds__(256) void k_embed(const ushort_t* __restrict__ xs,
        const int* __restrict__ flags, const float* __restrict__ W,
        const float* __restrict__ b, const float* __restrict__ dinv,
        __half* __restrict__ h16, __half* __restrict__ ht16, float* __restrict__ mxs, int N){
    __shared__ float Wt[64*64];
    if (blockIdx.x == 0 && threadIdx.x < 8) ((unsigned*)mxs)[threadIdx.x] = 0u;  // encoded -inf
    for (int idx = threadIdx.x; idx < 4096; idx += 256){
        int k = idx >> 6, j = idx & 63;
        Wt[idx] = W[j*64+k];
    }
    __syncthreads();
    int fl = flags[0];
    int lane = threadIdx.x & 63;
    int wid  = (blockIdx.x*blockDim.x + threadIdx.x) >> 6;
    int nw   = (gridDim.x*blockDim.x) >> 6;
    float bj = b[lane];
    for (int v = wid; v < N; v += nw){
        float xj = decode_slot(xs, (long long)v*64 + lane, fl);
        float acc = bj;
        #pragma unroll
        for (int k = 0; k < 64; k++) acc += __shfl(xj, k) * Wt[k*64+lane];
        h16[(size_t)v*64 + lane] = __float2half(acc);
        ht16[(size_t)v*64 + lane] = __float2half(dinv[v]*acc);
    }
}

// ---------- per-layer (MFMA): G16 = h16 @ gat_W; a_s/a_d via att-folded 5th tile ----------
__global__ __launch_bounds__(256) void k_gat_g(const __half* __restrict__ h16,
        const _Float16* __restrict__ Bg, __half* __restrict__ G16,
        float* __restrict__ a_s, float* __restrict__ a_d, float* __restrict__ mxs, int N){
    __shared__ float redm[4][8];
    int lane = threadIdx.x & 63;
    int wv = threadIdx.x >> 6;
    int q = lane >> 4, c = lane & 15;
    half8 B[5][2];
    const half8* Bp = (const half8*)Bg;
    #pragma unroll
    for (int t = 0; t < 5; t++)
        #pragma unroll
        for (int kk = 0; kk < 2; kk++)
            B[t][kk] = Bp[(t*2+kk)*64 + lane];
    float lmax = -1e30f;
    int tiles = (N + 15) >> 4;
    int wid = (blockIdx.x*blockDim.x + threadIdx.x) >> 6;
    int nw  = (gridDim.x*blockDim.x) >> 6;
    for (int tile = wid; tile < tiles; tile += nw){
        int nb = tile << 4;
        int anode = nb + c; if (anode >= N) anode = N - 1;
        const half8* ap = (const half8*)(h16 + (size_t)anode*64);
        half8 A0 = ap[q];
        half8 A1 = ap[4 + q];
        f32x4 acc[5];
        #pragma unroll
        for (int t = 0; t < 5; t++){
            f32x4 z = {0.f, 0.f, 0.f, 0.f};
            z = __builtin_amdgcn_mfma_f32_16x16x32_f16(A0, B[t][0], z, 0, 0, 0);
            z = __builtin_amdgcn_mfma_f32_16x16x32_f16(A1, B[t][1], z, 0, 0, 0);
            acc[t] = z;
        }
        #pragma unroll
        for (int r = 0; r < 4; r++) lmax = fmaxf(lmax, acc[4][r]);
        #pragma unroll
        for (int r = 0; r < 4; r++){
            int node = nb + q*4 + r;
            if (node < N){
                #pragma unroll
                for (int t = 0; t < 4; t++)
                    G16[(size_t)node*64 + t*16 + c] = __float2half(acc[t][r]);
                if (c < 8){
                    int hx = c >> 1;
                    if (c & 1) a_d[node*4+hx] = acc[4][r];
                    else       a_s[node*4+hx] = acc[4][r];
                }
            }
        }
    }
    lmax = fmaxf(lmax, __shfl_xor(lmax, 16));
    lmax = fmaxf(lmax, __shfl_xor(lmax, 32));
    if (lane < 8) redm[wv][lane] = lmax;
    __syncthreads();
    if (threadIdx.x < 8){
        float m = fmaxf(fmaxf(redm[0][threadIdx.x], redm[1][threadIdx.x]),
                        fmaxf(redm[2][threadIdx.x], redm[3][threadIdx.x]));
        int hx = threadIdx.x >> 1;
        int ix = (threadIdx.x & 1) ? 4 + hx : hx;
        atomicMax((unsigned*)mxs + ix, encf(m));
    }
}

__device__ __forceinline__ float leaky(float t){ return t > 0.f ? t : NEG*t; }

// ---------- gather: 8 nodes/wave, 8 lanes/node, 16B loads ----------
// v7: non-temporal hints on the read-once/write-once streams (CSR indices in,
// Aj16/xg16 out) so they stop evicting the hot 12.8MB tables from per-XCD L2.
// Tables (ht16/G16) and small a_s/a_d stay cacheable.
__global__ __launch_bounds__(256) void k_gather(const __half* __restrict__ ht16,
        const __half* __restrict__ G16,
        const float* __restrict__ a_s, const float* __restrict__ a_d,
        const float* __restrict__ mxs, const float* __restrict__ dinv,
        const int* __restrict__ row_ptr, const int* __restrict__ re_col,
        const int* __restrict__ col_ptr, const int* __restrict__ ce_row,
        __half* __restrict__ Aj16, __half* __restrict__ xg16, int N){
    int lane = threadIdx.x & 63;
    int grp  = lane >> 3;
    int sub  = lane & 7;
    int hh   = sub >> 1;
    int wid  = (blockIdx.x*blockDim.x + threadIdx.x) >> 6;
    int v    = wid*8 + grp;
    if (v >= N) return;
    const us8* htb = (const us8*)ht16;
    const us8* gb  = (const us8*)G16;
    const unsigned* mu = (const unsigned*)mxs;
    float sh = leaky(decf(mu[hh]) + decf(mu[4+hh]));
    int rs = __builtin_nontemporal_load(&row_ptr[v]);
    int re = __builtin_nontemporal_load(&row_ptr[v+1]);
    float a0[8] = {0,0,0,0,0,0,0,0}, a1[8] = {0,0,0,0,0,0,0,0};
    float a2[8] = {0,0,0,0,0,0,0,0}, a3[8] = {0,0,0,0,0,0,0,0};
    int i = rs;
    for (; i + 3 < re; i += 4){
        int c0 = __builtin_nontemporal_load(&re_col[i]);
        int c1 = __builtin_nontemporal_load(&re_col[i+1]);
        int c2 = __builtin_nontemporal_load(&re_col[i+2]);
        int c3 = __builtin_nontemporal_load(&re_col[i+3]);
        us8 q0 = htb[(size_t)c0*8 + sub];
        us8 q1 = htb[(size_t)c1*8 + sub];
        us8 q2 = htb[(size_t)c2*8 + sub];
        us8 q3 = htb[(size_t)c3*8 + sub];
        #pragma unroll
        for (int j = 0; j < 8; j++){
            a0[j] += __half2float(__ushort_as_half(q0[j]));
            a1[j] += __half2float(__ushort_as_half(q1[j]));
            a2[j] += __half2float(__ushort_as_half(q2[j]));
            a3[j] += __half2float(__ushort_as_half(q3[j]));
        }
    }
    for (; i < re; i++){
        int c0 = __builtin_nontemporal_load(&re_col[i]);
        us8 q0 = htb[(size_t)c0*8 + sub];
        #pragma unroll
        for (int j = 0; j < 8; j++) a0[j] += __half2float(__ushort_as_half(q0[j]));
    }
    float dv = dinv[v];
    us8 pa;
    #pragma unroll
    for (int j = 0; j < 8; j++)
        pa[j] = __half_as_ushort(__float2half(dv*((a0[j]+a1[j]) + (a2[j]+a3[j]))));
    __builtin_nontemporal_store(pa, &((us8*)Aj16)[(size_t)v*8 + sub]);
    float adv = a_d[v*4+hh];
    float eesl = __expf(leaky(a_s[v*4+hh] + adv) - sh);
    float s0 = eesl, s1 = 0.f, s2 = 0.f, s3 = 0.f;
    {
        us8 g0 = gb[(size_t)v*8 + sub];
        #pragma unroll
        for (int j = 0; j < 8; j++){
            a0[j] = eesl * __half2float(__ushort_as_half(g0[j]));
            a1[j] = 0.f; a2[j] = 0.f; a3[j] = 0.f;
        }
    }
    int cs = __builtin_nontemporal_load(&col_ptr[v]);
    int ce = __builtin_nontemporal_load(&col_ptr[v+1]);
    i = cs;
    for (; i + 3 < ce; i += 4){
        int r0 = __builtin_nontemporal_load(&ce_row[i]);
        int r1 = __builtin_nontemporal_load(&ce_row[i+1]);
        int r2 = __builtin_nontemporal_load(&ce_row[i+2]);
        int r3 = __builtin_nontemporal_load(&ce_row[i+3]);
        float e0 = __expf(leaky(a_s[r0*4+hh] + adv) - sh);
        float e1 = __expf(leaky(a_s[r1*4+hh] + adv) - sh);
        float e2 = __expf(leaky(a_s[r2*4+hh] + adv) - sh);
        float e3 = __expf(leaky(a_s[r3*4+hh] + adv) - sh);
        us8 q0 = gb[(size_t)r0*8 + sub];
        us8 q1 = gb[(size_t)r1*8 + sub];
        us8 q2 = gb[(size_t)r2*8 + sub];
        us8 q3 = gb[(size_t)r3*8 + sub];
        #pragma unroll
        for (int j = 0; j < 8; j++){
            a0[j] += e0 * __half2float(__ushort_as_half(q0[j]));
            a1[j] += e1 * __half2float(__ushort_as_half(q1[j]));
            a2[j] += e2 * __half2float(__ushort_as_half(q2[j]));
            a3[j] += e3 * __half2float(__ushort_as_half(q3[j]));
        }
        s0 += e0; s1 += e1; s2 += e2; s3 += e3;
    }
    for (; i < ce; i++){
        int r0 = __builtin_nontemporal_load(&ce_row[i]);
        float e0 = __expf(leaky(a_s[r0*4+hh] + adv) - sh);
        us8 q0 = gb[(size_t)r0*8 + sub];
        #pragma unroll
        for (int j = 0; j < 8; j++) a0[j] += e0 * __half2float(__ushort_as_half(q0[j]));
        s0 += e0;
    }
    float inv = 1.f/((s0+s1)+(s2+s3));
    us8 px;
    #pragma unroll
    for (int j = 0; j < 8; j++)
        px[j] = __half_as_ushort(__float2half(((a0[j]+a1[j]) + (a2[j]+a3[j]))*inv));
    __builtin_nontemporal_store(px, &((us8*)xg16)[(size_t)v*8 + sub]);
}

// ---------- fuse (MFMA): y = [Aj|xg] @ W, + bias + residual(h16) + LN + ReLU ----------
__global__ __launch_bounds__(256) void k_fuse(
        const __half* __restrict__ Aj16, const __half* __restrict__ xg16,
        const float* __restrict__ dinv, __half* __restrict__ h16,
        __half* __restrict__ ht16,
        const _Float16* __restrict__ Bfrag, const float* __restrict__ b2c,
        const float* __restrict__ ln_g, const float* __restrict__ ln_b,
        float* __restrict__ mxs, int N){
    if (blockIdx.x == 0 && threadIdx.x < 8) ((unsigned*)mxs)[threadIdx.x] = 0u;
    int lane = threadIdx.x & 63;
    int q = lane >> 4, c = lane & 15;
    half8 B[4][4];
    const half8* Bp = (const half8*)Bfrag;
    #pragma unroll
    for (int t = 0; t < 4; t++)
        #pragma unroll
        for (int kk = 0; kk < 4; kk++)
            B[t][kk] = Bp[(t*4+kk)*64 + lane];
    float bj[4], lg[4], lb[4];
    #pragma unroll
    for (int t = 0; t < 4; t++){
        int n = t*16 + c;
        bj[t] = b2c[n]; lg[t] = ln_g[n]; lb[t] = ln_b[n];
    }
    int tiles = (N + 15) >> 4;
    int wid = (blockIdx.x*blockDim.x + threadIdx.x) >> 6;
    int nw  = (gridDim.x*blockDim.x) >> 6;
    for (int tile = wid; tile < tiles; tile += nw){
        int nb = tile << 4;
        int anode = nb + c; if (anode >= N) anode = N - 1;
        const half8* ap = (const half8*)(Aj16 + (size_t)anode*64);
        const half8* xp = (const half8*)(xg16 + (size_t)anode*64);
        half8 A0 = ap[q];
        half8 A1 = ap[4 + q];
        half8 A2 = xp[q];
        half8 A3 = xp[4 + q];
        f32x4 acc[4];
        #pragma unroll
        for (int t = 0; t < 4; t++){
            f32x4 z = {0.f, 0.f, 0.f, 0.f};
            z = __builtin_amdgcn_mfma_f32_16x16x32_f16(A0, B[t][0], z, 0, 0, 0);
            z = __builtin_amdgcn_mfma_f32_16x16x32_f16(A1, B[t][1], z, 0, 0, 0);
            z = __builtin_amdgcn_mfma_f32_16x16x32_f16(A2, B[t][2], z, 0, 0, 0);
            z = __builtin_amdgcn_mfma_f32_16x16x32_f16(A3, B[t][3], z, 0, 0, 0);
            acc[t] = z;
        }
        float y[4][4];     // [t][r]
        #pragma unroll
        for (int r = 0; r < 4; r++){
            int node = nb + q*4 + r;
            int nd = node < N ? node : N - 1;
            #pragma unroll
            for (int t = 0; t < 4; t++)
                y[t][r] = acc[t][r] + bj[t]
                        + __half2float(h16[(size_t)nd*64 + t*16 + c]);
        }
        #pragma unroll
        for (int r = 0; r < 4; r++){
            int node = nb + q*4 + r;
            float s = (y[0][r] + y[1][r]) + (y[2][r] + y[3][r]);
            #pragma unroll
            for (int o = 1; o < 16; o <<= 1) s += __shfl_xor(s, o);
            float mu = s * (1.f/64.f);
            float d0 = y[0][r]-mu, d1 = y[1][r]-mu, d2 = y[2][r]-mu, d3 = y[3][r]-mu;
            float var = (d0*d0 + d1*d1) + (d2*d2 + d3*d3);
            #pragma unroll
            for (int o = 1; o < 16; o <<= 1) var += __shfl_xor(var, o);
            var *= (1.f/64.f);
            float rstd = rsqrtf(var + LNEPS);
            if (node < N){
                float dvv = dinv[node];
                #pragma unroll
                for (int t = 0; t < 4; t++){
                    float out = (y[t][r]-mu)*rstd*lg[t] + lb[t];
                    out = out > 0.f ? out : 0.f;
                    h16[(size_t)node*64 + t*16 + c] = __float2half(out);
                    ht16[(size_t)node*64 + t*16 + c] = __float2half(dvv*out);
                }
            }
        }
    }
}

// ---------- readout (h16 input) ----------
__global__ __launch_bounds__(256) void k_readout(const __half* __restrict__ h16,
        const float* __restrict__ W1, const float* __restrict__ b1,
        const float* __restrict__ W2, const float* __restrict__ b2,
        float* __restrict__ out, int N){
    __shared__ float W1t[64*32];
    for (int idx = threadIdx.x; idx < 2048; idx += 256){
        int k = idx >> 5, j = idx & 31;
        W1t[idx] = W1[j*64+k];
    }
    __syncthreads();
    int lane = threadIdx.x & 63;
    float w2  = (lane < 32) ? W2[lane] : 0.f;
    float b1v = (lane < 32) ? b1[lane] : 0.f;
    float b2v = b2[0];
    int wid = (blockIdx.x*blockDim.x + threadIdx.x) >> 6;
    int nw  = (gridDim.x*blockDim.x) >> 6;
    for (int v = wid; v < N; v += nw){
        float hj = __half2float(h16[(size_t)v*64+lane]);
        float acc = b1v;
        #pragma unroll
        for (int k = 0; k < 64; k++){
            float hk = __shfl(hj, k);
            if (lane < 32) acc += hk * W1t[k*32+lane];
        }
        float h1 = acc > 0.f ? acc : 0.f;
        float p = h1 * w2;
        #pragma unroll
        for (int o = 1; o < 32; o <<= 1) p += __shfl_xor(p, o);
        if (lane == 0){
            float z = p + b2v;
            out[v] = 1.f/(1.f + __expf(-z));
        }
    }
}

extern "C" void kernel_launch(void* const* d_in, const int* in_sizes, int n_in,
                              void* d_out, int out_size, void* d_ws, size_t ws_size,
                              hipStream_t stream){
    const ushort_t* xs = (const ushort_t*)d_in[0];
    const int*      ei = (const int*)d_in[1];

    int N = in_sizes[0] / 64;
    int E = in_sizes[1] / 2;
    const int* row = ei;
    const int* col = ei + E;
    int NBK = (N + BWD - 1) / BWD;

    size_t stageF = (size_t)2*E;
    size_t mirF   = (size_t)N*32;
    size_t aliasF = stageF > mirF ? stageF : mirF;

    float* f = (float*)d_ws;
    size_t o = 0;
    int*   flags = (int*)(f + o); o += 16;
    float* P     = f + o; o += P_TOTAL + 63;
    __half* h16  = (__half*)(f + o); o += mirF;
    __half* ht16 = (__half*)(f + o); o += mirF;
    __half* G16  = (__half*)(f + o); o += mirF;
    __half* Aj16 = (__half*)(f + o); size_t aoff = o; o += aliasF;
    __half* xg16 = (__half*)(f + o); size_t xoff = o; o += aliasF;
    uint2* stage_r = (uint2*)(f + aoff);
    uint2* stage_c = (uint2*)(f + xoff);
    float* a_s   = f + o; o += (size_t)N*4;
    float* a_d   = f + o; o += (size_t)N*4;
    float* mxs   = f + o; o += 16;
    float* dinv  = f + o; o += ((size_t)N + 15) & ~15ull;
    int* bcnt    = (int*)(f + o); o += 512;
    int* bptr_r  = (int*)(f + o); o += 512;
    int* bptr_c  = (int*)(f + o); o += 512;
    int* bcur_r  = (int*)(f + o); o += 512;
    int* bcur_c  = (int*)(f + o); o += 512;
    int* ptr_r   = (int*)(f + o); o += ((size_t)N + 16) & ~15ull;
    int* ptr_c   = (int*)(f + o); o += ((size_t)N + 16) & ~15ull;
    int* re_col  = (int*)(f + o); o += (size_t)E;
    int* ce_row  = (int*)(f + o); o += (size_t)E;
    float* W1c   = f + o; o += 3*4096;
    float* b2c   = f + o; o += 3*64;
    _Float16* Bfrag = (_Float16*)(f + o); o += 3*4096;   // 3*8192 fp16
    _Float16* Bg    = (_Float16*)(f + o); o += 3*2560;   // 3*5120 fp16 (5 t-tiles)

    const float* emb_W   = P + 0;
    const float* emb_b   = P + 4096;
    const float* e8_W    = P + 4160;
    const float* gat_W   = P + 16448;
    const float* att_src = P + 28736;
    const float* att_dst = P + 28928;
    const float* gat_b   = P + 29120;
    const float* fus_W   = P + 29312;
    const float* fus_b   = P + 53888;
    const float* ln_g    = P + 54080;
    const float* ln_b    = P + 54272;
    const float* r_W1    = P + 54464;
    const float* r_b1    = P + 56512;
    const float* r_W2    = P + 56544;
    const float* r_b2    = P + 56576;

    k_detect<<<1, 64, 0, stream>>>(d_in[0], d_in[2], d_in[4], d_in[5], d_in[6], d_in[7],
                                   d_in[9], d_in[13], d_in[15], d_in[11], flags);
    k_convert<<<(P_TOTAL+255)/256, 256, 0, stream>>>(
        d_in[2],d_in[3],d_in[4],d_in[5],d_in[6],d_in[7],d_in[8],d_in[9],
        d_in[10],d_in[11],d_in[12],d_in[13],d_in[14],d_in[15],d_in[16], flags, P);

    hipMemsetAsync(bcnt, 0, 512*sizeof(int), stream);
    kb_hist<<<256, 1024, 0, stream>>>(row, col, bcnt, NBK, E);
    kb_scan<<<2, 256, 0, stream>>>(bcnt, bptr_r, bptr_c, bcur_r, bcur_c, NBK, E);
    kb_bin<<<256, 1024, 0, stream>>>(row, col, bcur_r, stage_r, NBK, E);
    kb_bin<<<256, 1024, 0, stream>>>(col, row, bcur_c, stage_c, NBK, E);
    kb_place<<<NBK, 1024, 0, stream>>>(stage_r, bptr_r, ptr_r, re_col, dinv, 0, N, E);
    kb_place<<<NBK, 1024, 0, stream>>>(stage_c, bptr_c, ptr_c, ce_row, dinv, 1, N, E);

    k_prew<<<48, 256, 0, stream>>>(fus_W, e8_W, gat_b, fus_b, W1c, b2c);
    k_prewB<<<(3*8192+255)/256, 256, 0, stream>>>(W1c, fus_W, Bfrag);
    k_prewBg<<<(3*5120+255)/256, 256, 0, stream>>>(gat_W, att_src, att_dst, Bg);
    k_embed<<<1024, 256, 0, stream>>>(xs, flags, emb_W, emb_b, dinv, h16, ht16, mxs, N);

    int ggrid = (N + 31) / 32;
    int tiles = (N + 15) / 16;
    int fgrid = (tiles + 7) / 8;
    for (int i = 0; i < 3; i++){
        k_gat_g<<<fgrid, 256, 0, stream>>>(h16, Bg + (size_t)i*5120,
                                           G16, a_s, a_d, mxs, N);
        k_gather<<<ggrid, 256, 0, stream>>>(ht16, G16, a_s, a_d, mxs, dinv,
                                            ptr_r, re_col, ptr_c, ce_row,
                                            Aj16, xg16, N);
        k_fuse<<<fgrid, 256, 0, stream>>>(Aj16, xg16, dinv, h16, ht16,
                                          Bfrag + (size_t)i*8192, b2c + i*64,
                                          ln_g + i*64, ln_b + i*64, mxs, N);
    }
    k_readout<<<1024, 256, 0, stream>>>(h16, r_W1, r_b1, r_W2, r_b2, (float*)d_out, N);
}

// Round 9
// 808.603 us; speedup vs baseline: 1.1064x; 1.1064x over previous
//
#include <hip/hip_runtime.h>
#include <hip/hip_bf16.h>
#include <hip/hip_fp16.h>

typedef __hip_bfloat16 bf16;
typedef unsigned short ushort_t;
typedef unsigned short us8 __attribute__((ext_vector_type(8)));
typedef _Float16 half8 __attribute__((ext_vector_type(8)));
typedef float f32x4 __attribute__((ext_vector_type(4)));

#define NEG 0.2f
#define LNEPS 1e-5f
#define BWD 512                 // CSR bucket width (nodes)

__device__ __forceinline__ int plaus(unsigned int lo){
    lo &= 0x7FFFu;
    if (lo == 0) return 1;
    unsigned int ex = (lo >> 7) & 0xFF;
    return (ex >= 100 && ex <= 140) ? 1 : 0;
}

__device__ __forceinline__ float decode_slot(const ushort_t* s, long long i, int fl){
    long long base = i << fl;
    unsigned int hi = s[base + fl];
    unsigned int lo = s[base];
    unsigned int bits = (hi << 16) | (lo * (unsigned int)fl);
    return __uint_as_float(bits);
}

// order-preserving float<->uint encoding for atomicMax on floats (incl. negatives)
__device__ __forceinline__ unsigned encf(float f){
    int b = __float_as_int(f);
    return (b >= 0) ? ((unsigned)b | 0x80000000u) : (unsigned)(~b);
}
__device__ __forceinline__ float decf(unsigned k){
    return (k & 0x80000000u) ? __uint_as_float(k & 0x7FFFFFFFu)
                             : __uint_as_float(~k);
}

// ---------- init: param convert (inline dtype detect) + flags + zero bcnt/mxs ----------
#define P_TOTAL 56577
__global__ void k_init(const void* p0, const void* p1, const void* p2, const void* p3,
        const void* p4, const void* p5, const void* p6, const void* p7, const void* p8,
        const void* p9, const void* p10, const void* p11, const void* p12, const void* p13,
        const void* p14, const void* xs, int* flags, float* P, int* bcnt, unsigned* mxsu){
    int t = threadIdx.x;
    if (blockIdx.x == 0){
        if (t < 9){
            const void* dt[9] = {xs, p0, p2, p3, p4, p5, p7, p11, p13};
            const ushort_t* w = (const ushort_t*)dt[t];
            int all_bf = 1;
            for (int i = 0; i < 16; i++) all_bf &= plaus((unsigned int)w[i]);
            flags[t] = all_bf ? 0 : 1;
        } else if (t == 9){
            const ushort_t* w = (const ushort_t*)p9;
            flags[9] = (w[0] == 0x3F80u) ? 0 : 1;
        }
        bcnt[t] = 0; bcnt[256 + t] = 0;
        if (t < 32) mxsu[t] = 0u;            // encoded -inf for 3 layer slots
    }
    int idx = blockIdx.x*blockDim.x + threadIdx.x;
    if (idx >= P_TOTAL) return;
    const int sizes[15] = {4096,64,12288,12288,192,192,192,24576,192,192,192,2048,32,32,1};
    const int fidx[15]  = {1,  -1,  2,    3,    4,  5,  -1, 6,    -1, 9,  -1, 7,   -1,8, -1};
    const void* ptrs[15] = {p0,p1,p2,p3,p4,p5,p6,p7,p8,p9,p10,p11,p12,p13,p14};
    int s = 0, base = 0;
    while (idx - base >= sizes[s]){ base += sizes[s]; s++; }
    int li = idx - base;
    int fi = fidx[s];
    int fl = 0;
    if (fi == 9){
        const ushort_t* w = (const ushort_t*)ptrs[s];
        fl = (w[0] == 0x3F80u) ? 0 : 1;
    } else if (fi >= 0){
        const ushort_t* w = (const ushort_t*)ptrs[s];
        int all_bf = 1;
        for (int i = 0; i < 16; i++) all_bf &= plaus((unsigned int)w[i]);
        fl = all_bf ? 0 : 1;
    }
    P[idx] = decode_slot((const ushort_t*)ptrs[s], li, fl);
}

// ---------- bucketed CSR build ----------
__global__ __launch_bounds__(1024) void kb_hist(const int* __restrict__ row,
        const int* __restrict__ col, int* __restrict__ bcnt, int NBK, int E){
    __shared__ int lh[512];
    int t = threadIdx.x;
    for (int i = t; i < 2*NBK; i += 1024) lh[i] = 0;
    __syncthreads();
    for (long long e = (long long)blockIdx.x*1024 + t; e < E; e += (long long)gridDim.x*1024){
        atomicAdd(&lh[row[e] >> 9], 1);
        atomicAdd(&lh[NBK + (col[e] >> 9)], 1);
    }
    __syncthreads();
    for (int i = t; i < 2*NBK; i += 1024){
        int v = lh[i];
        if (v) atomicAdd(&bcnt[i], v);
    }
}

__global__ __launch_bounds__(256) void kb_scan(const int* __restrict__ bcnt,
        int* __restrict__ bptr_r, int* __restrict__ bptr_c,
        int* __restrict__ bcur_r, int* __restrict__ bcur_c, int NBK, int E){
    __shared__ int sh[256];
    int side = blockIdx.x;
    const int* c = bcnt + side*NBK;
    int* bp = side ? bptr_c : bptr_r;
    int* bc = side ? bcur_c : bcur_r;
    int t = threadIdx.x;
    int v = (t < NBK) ? c[t] : 0;
    sh[t] = v; __syncthreads();
    for (int off = 1; off < 256; off <<= 1){
        int add = (t >= off) ? sh[t-off] : 0;
        __syncthreads();
        sh[t] += add;
        __syncthreads();
    }
    if (t < NBK){ int e = sh[t] - v; bp[t] = e; bc[t] = e; }
    if (t == 0) bp[NBK] = E;
}

// both sides in one launch: blocks 0..255 row-keyed, 256..511 col-keyed
__global__ __launch_bounds__(1024) void kb_bin(const int* __restrict__ row,
        const int* __restrict__ col, int* __restrict__ bcur_r, int* __restrict__ bcur_c,
        uint2* __restrict__ stage_r, uint2* __restrict__ stage_c, int NBK, int E){
    __shared__ int lh[256], lbase[256];
    int side = blockIdx.x >> 8;
    int bid  = blockIdx.x & 255;
    const int* key = side ? col : row;
    const int* pay = side ? row : col;
    int* bcur = side ? bcur_c : bcur_r;
    uint2* stage = side ? stage_c : stage_r;
    int t = threadIdx.x;
    for (long long tile = (long long)bid*1024; tile < E; tile += (long long)256*1024){
        for (int i = t; i < NBK; i += 1024) lh[i] = 0;
        __syncthreads();
        int e = (int)tile + t;
        int k = 0, p = 0, b = -1, rank = 0;
        if (e < E){
            k = key[e]; p = pay[e]; b = k >> 9;
            rank = atomicAdd(&lh[b], 1);
        }
        __syncthreads();
        for (int i = t; i < NBK; i += 1024){
            int c = lh[i];
            lbase[i] = c ? atomicAdd(&bcur[i], c) : 0;
        }
        __syncthreads();
        if (b >= 0) stage[lbase[b] + rank] = make_uint2((unsigned)k, (unsigned)p);
        __syncthreads();
    }
}

// both sides in one launch: blocks 0..NBK-1 row, NBK..2NBK-1 col
__global__ __launch_bounds__(1024) void kb_place(const uint2* __restrict__ stage_r,
        const uint2* __restrict__ stage_c, const int* __restrict__ bptr_r,
        const int* __restrict__ bptr_c, int* __restrict__ ptr_r, int* __restrict__ ptr_c,
        int* __restrict__ re_col, int* __restrict__ ce_row,
        float* __restrict__ dinv, int NBK, int N, int E){
    __shared__ int lcnt[BWD], lsc[BWD], lcur[BWD];
    int side = blockIdx.x >= NBK;
    int b = blockIdx.x - (side ? NBK : 0);
    const uint2* stage = side ? stage_c : stage_r;
    const int* bptr = side ? bptr_c : bptr_r;
    int* ptr = side ? ptr_c : ptr_r;
    int* outarr = side ? ce_row : re_col;
    int wantdinv = side;
    int s = bptr[b], e = bptr[b+1];
    int nbase = b << 9;
    int t = threadIdx.x;
    if (t < BWD) lcnt[t] = 0;
    __syncthreads();
    for (int i = s + t; i < e; i += 1024)
        atomicAdd(&lcnt[stage[i].x - nbase], 1);
    __syncthreads();
    if (t < BWD) lsc[t] = lcnt[t];
    __syncthreads();
    for (int off = 1; off < BWD; off <<= 1){
        int add = (t >= off && t < BWD) ? lsc[t-off] : 0;
        __syncthreads();
        if (t < BWD) lsc[t] += add;
        __syncthreads();
    }
    if (t < BWD){
        int node = nbase + t;
        int excl = lsc[t] - lcnt[t];
        lcur[t] = excl;
        if (node < N){
            ptr[node] = s + excl;
            if (wantdinv) dinv[node] = lcnt[t] > 0 ? rsqrtf((float)lcnt[t]) : 0.f;
        }
    }
    if (b == 0 && t == 0) ptr[N] = E;
    __syncthreads();
    for (int i = s + t; i < e; i += 1024){
        uint2 rec = stage[i];
        int pos = s + atomicAdd(&lcur[rec.x - nbase], 1);
        outarr[pos] = (int)rec.y;
    }
}

// ---------- merged weight precompute: Bfrag (with folded e8) + b2c ----------
#define PRW_B0 (3*8192)
#define PRW_B1 (PRW_B0 + 192)
__global__ void k_prew_all(const float* __restrict__ fus_W, const float* __restrict__ e8_W,
        const float* __restrict__ gat_b, const float* __restrict__ fus_b,
        _Float16* __restrict__ Bfrag, float* __restrict__ b2c){
    int idx = blockIdx.x*blockDim.x + threadIdx.x;
    if (idx < PRW_B0){
        int i = idx / 8192; int rem = idx & 8191;
        int j = rem & 7, lane = (rem >> 3) & 63, kk = (rem >> 9) & 3, t = rem >> 11;
        int k = kk*32 + (lane >> 4)*8 + j;
        int n = t*16 + (lane & 15);
        float v;
        if (k < 64){
            const float* fw = fus_W + (size_t)i*8192 + (size_t)n*128;
            const float* ew = e8_W + (size_t)i*4096;
            float acc = 0.f;
            for (int p = 0; p < 64; p++) acc += fw[p] * ew[p*64 + k];
            v = acc;
        } else {
            v = fus_W[(size_t)i*8192 + (size_t)n*128 + 64 + (k - 64)];
        }
        Bfrag[idx] = (_Float16)v;
    } else if (idx < PRW_B1){
        int t2 = idx - PRW_B0;
        int i = t2 >> 6, j = t2 & 63;
        const float* fw = fus_W + (size_t)i*8192 + (size_t)j*128 + 64;
        float acc = fus_b[i*64+j];
        for (int p = 0; p < 64; p++) acc += gat_b[i*64+p] * fw[p];
        b2c[t2] = acc;
    }
}

// ---------- Bg build: 5 t-tiles x 2 kk-steps (t=4: att-folded projections) ----------
__global__ void k_prew_bg(const float* __restrict__ gat_W, const float* __restrict__ att_src,
                          const float* __restrict__ att_dst, _Float16* __restrict__ Bg){
    int idx = blockIdx.x*blockDim.x + threadIdx.x;
    if (idx >= 3*5120) return;
    int i = idx / 5120; int rem = idx % 5120;
    int j = rem & 7, lane = (rem >> 3) & 63, kk = (rem >> 9) & 1, t = rem >> 10;
    int k = kk*32 + (lane >> 4)*8 + j;
    int nn = lane & 15;
    float v;
    if (t < 4){
        v = gat_W[(size_t)i*4096 + k*64 + (t*16 + nn)];
    } else if (nn < 8){
        int hx = nn >> 1;
        const float* att = (nn & 1) ? att_dst : att_src;
        float acc = 0.f;
        for (int c = 0; c < 16; c++)
            acc += gat_W[(size_t)i*4096 + k*64 + hx*16 + c] * att[i*64 + hx*16 + c];
        v = acc;
    } else {
        v = 0.f;
    }
    Bg[idx] = (_Float16)v;
}

// ---------- embedding: h16 + ht16 = dinv*h ----------
__global__ __launch_bounds__(256) void k_embed(const ushort_t* __restrict__ xs,
        const int* __restrict__ flags, const float* __restrict__ W,
        const float* __restrict__ b, const float* __restrict__ dinv,
        __half* __restrict__ h16, __half* __restrict__ ht16, int N){
    __shared__ float Wt[64*64];
    for (int idx = threadIdx.x; idx < 4096; idx += 256){
        int k = idx >> 6, j = idx & 63;
        Wt[idx] = W[j*64+k];
    }
    __syncthreads();
    int fl = flags[0];
    int lane = threadIdx.x & 63;
    int wid  = (blockIdx.x*blockDim.x + threadIdx.x) >> 6;
    int nw   = (gridDim.x*blockDim.x) >> 6;
    float bj = b[lane];
    for (int v = wid; v < N; v += nw){
        float xj = decode_slot(xs, (long long)v*64 + lane, fl);
        float acc = bj;
        #pragma unroll
        for (int k = 0; k < 64; k++) acc += __shfl(xj, k) * Wt[k*64+lane];
        h16[(size_t)v*64 + lane] = __float2half(acc);
        ht16[(size_t)v*64 + lane] = __float2half(dinv[v]*acc);
    }
}

// ---------- layer-0 G projection (standalone; layers 1,2 fused into k_fuse_g) ----------
__global__ __launch_bounds__(256) void k_gat_g(const __half* __restrict__ h16,
        const _Float16* __restrict__ Bg, __half* __restrict__ G16,
        float* __restrict__ a_s, float* __restrict__ a_d, float* __restrict__ mxs, int N){
    __shared__ float redm[4][8];
    int lane = threadIdx.x & 63;
    int wv = threadIdx.x >> 6;
    int q = lane >> 4, c = lane & 15;
    half8 B[5][2];
    const half8* Bp = (const half8*)Bg;
    #pragma unroll
    for (int t = 0; t < 5; t++)
        #pragma unroll
        for (int kk = 0; kk < 2; kk++)
            B[t][kk] = Bp[(t*2+kk)*64 + lane];
    float lmax = -1e30f;
    int tiles = (N + 15) >> 4;
    int wid = (blockIdx.x*blockDim.x + threadIdx.x) >> 6;
    int nw  = (gridDim.x*blockDim.x) >> 6;
    for (int tile = wid; tile < tiles; tile += nw){
        int nb = tile << 4;
        int anode = nb + c; if (anode >= N) anode = N - 1;
        const half8* ap = (const half8*)(h16 + (size_t)anode*64);
        half8 A0 = ap[q];
        half8 A1 = ap[4 + q];
        f32x4 acc[5];
        #pragma unroll
        for (int t = 0; t < 5; t++){
            f32x4 z = {0.f, 0.f, 0.f, 0.f};
            z = __builtin_amdgcn_mfma_f32_16x16x32_f16(A0, B[t][0], z, 0, 0, 0);
            z = __builtin_amdgcn_mfma_f32_16x16x32_f16(A1, B[t][1], z, 0, 0, 0);
            acc[t] = z;
        }
        #pragma unroll
        for (int r = 0; r < 4; r++) lmax = fmaxf(lmax, acc[4][r]);
        #pragma unroll
        for (int r = 0; r < 4; r++){
            int node = nb + q*4 + r;
            if (node < N){
                #pragma unroll
                for (int t = 0; t < 4; t++)
                    G16[(size_t)node*64 + t*16 + c] = __float2half(acc[t][r]);
                if (c < 8){
                    int hx = c >> 1;
                    if (c & 1) a_d[node*4+hx] = acc[4][r];
                    else       a_s[node*4+hx] = acc[4][r];
                }
            }
        }
    }
    lmax = fmaxf(lmax, __shfl_xor(lmax, 16));
    lmax = fmaxf(lmax, __shfl_xor(lmax, 32));
    if (lane < 8) redm[wv][lane] = lmax;
    __syncthreads();
    if (threadIdx.x < 8){
        float m = fmaxf(fmaxf(redm[0][threadIdx.x], redm[1][threadIdx.x]),
                        fmaxf(redm[2][threadIdx.x], redm[3][threadIdx.x]));
        int hx = threadIdx.x >> 1;
        int ix = (threadIdx.x & 1) ? 4 + hx : hx;
        atomicMax((unsigned*)mxs + ix, encf(m));
    }
}

__device__ __forceinline__ float leaky(float t){ return t > 0.f ? t : NEG*t; }

// ---------- gather: 8 nodes/wave, 8 lanes/node, 16B loads (round-6 proven form) ----------
__global__ __launch_bounds__(256) void k_gather(const __half* __restrict__ ht16,
        const __half* __restrict__ G16,
        const float* __restrict__ a_s, const float* __restrict__ a_d,
        const float* __restrict__ mxs, const float* __restrict__ dinv,
        const int* __restrict__ row_ptr, const int* __restrict__ re_col,
        const int* __restrict__ col_ptr, const int* __restrict__ ce_row,
        __half* __restrict__ Aj16, __half* __restrict__ xg16, int N){
    int lane = threadIdx.x & 63;
    int grp  = lane >> 3;
    int sub  = lane & 7;
    int hh   = sub >> 1;
    int wid  = (blockIdx.x*blockDim.x + threadIdx.x) >> 6;
    int v    = wid*8 + grp;
    if (v >= N) return;
    const us8* htb = (const us8*)ht16;
    const us8* gb  = (const us8*)G16;
    const unsigned* mu = (const unsigned*)mxs;
    float sh = leaky(decf(mu[hh]) + decf(mu[4+hh]));
    int rs = row_ptr[v], re = row_ptr[v+1];
    float a0[8] = {0,0,0,0,0,0,0,0}, a1[8] = {0,0,0,0,0,0,0,0};
    float a2[8] = {0,0,0,0,0,0,0,0}, a3[8] = {0,0,0,0,0,0,0,0};
    int i = rs;
    for (; i + 3 < re; i += 4){
        us8 q0 = htb[(size_t)re_col[i]*8 + sub];
        us8 q1 = htb[(size_t)re_col[i+1]*8 + sub];
        us8 q2 = htb[(size_t)re_col[i+2]*8 + sub];
        us8 q3 = htb[(size_t)re_col[i+3]*8 + sub];
        #pragma unroll
        for (int j = 0; j < 8; j++){
            a0[j] += __half2float(__ushort_as_half(q0[j]));
            a1[j] += __half2float(__ushort_as_half(q1[j]));
            a2[j] += __half2float(__ushort_as_half(q2[j]));
            a3[j] += __half2float(__ushort_as_half(q3[j]));
        }
    }
    for (; i < re; i++){
        us8 q0 = htb[(size_t)re_col[i]*8 + sub];
        #pragma unroll
        for (int j = 0; j < 8; j++) a0[j] += __half2float(__ushort_as_half(q0[j]));
    }
    float dv = dinv[v];
    us8 pa;
    #pragma unroll
    for (int j = 0; j < 8; j++)
        pa[j] = __half_as_ushort(__float2half(dv*((a0[j]+a1[j]) + (a2[j]+a3[j]))));
    ((us8*)Aj16)[(size_t)v*8 + sub] = pa;
    float adv = a_d[v*4+hh];
    float eesl = __expf(leaky(a_s[v*4+hh] + adv) - sh);
    float s0 = eesl, s1 = 0.f, s2 = 0.f, s3 = 0.f;
    {
        us8 g0 = gb[(size_t)v*8 + sub];
        #pragma unroll
        for (int j = 0; j < 8; j++){
            a0[j] = eesl * __half2float(__ushort_as_half(g0[j]));
            a1[j] = 0.f; a2[j] = 0.f; a3[j] = 0.f;
        }
    }
    int cs = col_ptr[v], ce = col_ptr[v+1];
    i = cs;
    for (; i + 3 < ce; i += 4){
        int r0 = ce_row[i], r1 = ce_row[i+1], r2 = ce_row[i+2], r3 = ce_row[i+3];
        float e0 = __expf(leaky(a_s[r0*4+hh] + adv) - sh);
        float e1 = __expf(leaky(a_s[r1*4+hh] + adv) - sh);
        float e2 = __expf(leaky(a_s[r2*4+hh] + adv) - sh);
        float e3 = __expf(leaky(a_s[r3*4+hh] + adv) - sh);
        us8 q0 = gb[(size_t)r0*8 + sub];
        us8 q1 = gb[(size_t)r1*8 + sub];
        us8 q2 = gb[(size_t)r2*8 + sub];
        us8 q3 = gb[(size_t)r3*8 + sub];
        #pragma unroll
        for (int j = 0; j < 8; j++){
            a0[j] += e0 * __half2float(__ushort_as_half(q0[j]));
            a1[j] += e1 * __half2float(__ushort_as_half(q1[j]));
            a2[j] += e2 * __half2float(__ushort_as_half(q2[j]));
            a3[j] += e3 * __half2float(__ushort_as_half(q3[j]));
        }
        s0 += e0; s1 += e1; s2 += e2; s3 += e3;
    }
    for (; i < ce; i++){
        int r0 = ce_row[i];
        float e0 = __expf(leaky(a_s[r0*4+hh] + adv) - sh);
        us8 q0 = gb[(size_t)r0*8 + sub];
        #pragma unroll
        for (int j = 0; j < 8; j++) a0[j] += e0 * __half2float(__ushort_as_half(q0[j]));
        s0 += e0;
    }
    float inv = 1.f/((s0+s1)+(s2+s3));
    us8 px;
    #pragma unroll
    for (int j = 0; j < 8; j++)
        px[j] = __half_as_ushort(__float2half(((a0[j]+a1[j]) + (a2[j]+a3[j]))*inv));
    ((us8*)xg16)[(size_t)v*8 + sub] = px;
}

// ---------- fuse+G (layers 0,1): fusion epilogue + NEXT layer's G via LDS transpose ----------
// LDS tile[16][64] fp16 per wave, XOR-swizzled (byte ^= (node&7)<<4): write in C/D
// layout (<=2-way bank), read back as A-fragments (b128, <=2-way), then 10 MFMAs
// produce next-layer G16/a_s/a_d + head max.
__global__ __launch_bounds__(256) void k_fuse_g(
        const __half* __restrict__ Aj16, const __half* __restrict__ xg16,
        const float* __restrict__ dinv, __half* __restrict__ h16,
        __half* __restrict__ ht16,
        const _Float16* __restrict__ Bfrag, const float* __restrict__ b2c,
        const float* __restrict__ ln_g, const float* __restrict__ ln_b,
        const _Float16* __restrict__ Bgn, __half* __restrict__ G16,
        float* __restrict__ a_s, float* __restrict__ a_d,
        float* __restrict__ mxs_next, int N){
    __shared__ float redm[4][8];
    __shared__ _Float16 tbuf[4][1024];
    int lane = threadIdx.x & 63;
    int wv = threadIdx.x >> 6;
    int q = lane >> 4, c = lane & 15;
    _Float16* tb = tbuf[wv];
    half8 B[4][4];
    const half8* Bp = (const half8*)Bfrag;
    #pragma unroll
    for (int t = 0; t < 4; t++)
        #pragma unroll
        for (int kk = 0; kk < 4; kk++)
            B[t][kk] = Bp[(t*4+kk)*64 + lane];
    half8 Bg[5][2];
    const half8* Bgp = (const half8*)Bgn;
    #pragma unroll
    for (int t = 0; t < 5; t++)
        #pragma unroll
        for (int kk = 0; kk < 2; kk++)
            Bg[t][kk] = Bgp[(t*2+kk)*64 + lane];
    float bj[4], lg[4], lb[4];
    #pragma unroll
    for (int t = 0; t < 4; t++){
        int n = t*16 + c;
        bj[t] = b2c[n]; lg[t] = ln_g[n]; lb[t] = ln_b[n];
    }
    float lmax = -1e30f;
    int tiles = (N + 15) >> 4;
    int wid = (blockIdx.x*blockDim.x + threadIdx.x) >> 6;
    int nw  = (gridDim.x*blockDim.x) >> 6;
    for (int tile = wid; tile < tiles; tile += nw){
        int nb = tile << 4;
        int anode = nb + c; if (anode >= N) anode = N - 1;
        const half8* ap = (const half8*)(Aj16 + (size_t)anode*64);
        const half8* xp = (const half8*)(xg16 + (size_t)anode*64);
        half8 A0 = ap[q];
        half8 A1 = ap[4 + q];
        half8 A2 = xp[q];
        half8 A3 = xp[4 + q];
        f32x4 acc[4];
        #pragma unroll
        for (int t = 0; t < 4; t++){
            f32x4 z = {0.f, 0.f, 0.f, 0.f};
            z = __builtin_amdgcn_mfma_f32_16x16x32_f16(A0, B[t][0], z, 0, 0, 0);
            z = __builtin_amdgcn_mfma_f32_16x16x32_f16(A1, B[t][1], z, 0, 0, 0);
            z = __builtin_amdgcn_mfma_f32_16x16x32_f16(A2, B[t][2], z, 0, 0, 0);
            z = __builtin_amdgcn_mfma_f32_16x16x32_f16(A3, B[t][3], z, 0, 0, 0);
            acc[t] = z;
        }
        float y[4][4];     // [t][r]
        #pragma unroll
        for (int r = 0; r < 4; r++){
            int node = nb + q*4 + r;
            int nd = node < N ? node : N - 1;
            #pragma unroll
            for (int t = 0; t < 4; t++)
                y[t][r] = acc[t][r] + bj[t]
                        + __half2float(h16[(size_t)nd*64 + t*16 + c]);
        }
        #pragma unroll
        for (int r = 0; r < 4; r++){
            int node = nb + q*4 + r;
            float s = (y[0][r] + y[1][r]) + (y[2][r] + y[3][r]);
            #pragma unroll
            for (int o = 1; o < 16; o <<= 1) s += __shfl_xor(s, o);
            float mu = s * (1.f/64.f);
            float d0 = y[0][r]-mu, d1 = y[1][r]-mu, d2 = y[2][r]-mu, d3 = y[3][r]-mu;
            float var = (d0*d0 + d1*d1) + (d2*d2 + d3*d3);
            #pragma unroll
            for (int o = 1; o < 16; o <<= 1) var += __shfl_xor(var, o);
            var *= (1.f/64.f);
            float rstd = rsqrtf(var + LNEPS);
            int nd2 = q*4 + r;
            #pragma unroll
            for (int t = 0; t < 4; t++){
                float out = (y[t][r]-mu)*rstd*lg[t] + lb[t];
                out = out > 0.f ? out : 0.f;
                int byte = nd2*128 + (t*16 + c)*2;
                byte ^= (nd2 & 7) << 4;
                *(_Float16*)((char*)tb + byte) = (_Float16)out;
                if (node < N){
                    h16[(size_t)node*64 + t*16 + c] = __float2half(out);
                    ht16[(size_t)node*64 + t*16 + c] = __float2half(dinv[node]*out);
                }
            }
        }
        // transpose read: A-frag for next layer's G (same wave wrote tb; in-order DS)
        int b0 = (c*128 + 16*q) ^ ((c & 7) << 4);
        int b1 = (c*128 + 64 + 16*q) ^ ((c & 7) << 4);
        half8 A0g = *(half8*)((char*)tb + b0);
        half8 A1g = *(half8*)((char*)tb + b1);
        f32x4 gacc[5];
        #pragma unroll
        for (int t = 0; t < 5; t++){
            f32x4 z = {0.f, 0.f, 0.f, 0.f};
            z = __builtin_amdgcn_mfma_f32_16x16x32_f16(A0g, Bg[t][0], z, 0, 0, 0);
            z = __builtin_amdgcn_mfma_f32_16x16x32_f16(A1g, Bg[t][1], z, 0, 0, 0);
            gacc[t] = z;
        }
        #pragma unroll
        for (int r = 0; r < 4; r++) lmax = fmaxf(lmax, gacc[4][r]);
        #pragma unroll
        for (int r = 0; r < 4; r++){
            int node = nb + q*4 + r;
            if (node < N){
                #pragma unroll
                for (int t = 0; t < 4; t++)
                    G16[(size_t)node*64 + t*16 + c] = __float2half(gacc[t][r]);
                if (c < 8){
                    int hx = c >> 1;
                    if (c & 1) a_d[node*4+hx] = gacc[4][r];
                    else       a_s[node*4+hx] = gacc[4][r];
                }
            }
        }
    }
    lmax = fmaxf(lmax, __shfl_xor(lmax, 16));
    lmax = fmaxf(lmax, __shfl_xor(lmax, 32));
    if (lane < 8) redm[wv][lane] = lmax;
    __syncthreads();
    if (threadIdx.x < 8){
        float m = fmaxf(fmaxf(redm[0][threadIdx.x], redm[1][threadIdx.x]),
                        fmaxf(redm[2][threadIdx.x], redm[3][threadIdx.x]));
        int hx = threadIdx.x >> 1;
        int ix = (threadIdx.x & 1) ? 4 + hx : hx;
        atomicMax((unsigned*)mxs_next + ix, encf(m));
    }
}

// ---------- fuse (layer 2, plain) ----------
__global__ __launch_bounds__(256) void k_fuse(
        const __half* __restrict__ Aj16, const __half* __restrict__ xg16,
        const float* __restrict__ dinv, __half* __restrict__ h16,
        __half* __restrict__ ht16,
        const _Float16* __restrict__ Bfrag, const float* __restrict__ b2c,
        const float* __restrict__ ln_g, const float* __restrict__ ln_b, int N){
    int lane = threadIdx.x & 63;
    int q = lane >> 4, c = lane & 15;
    half8 B[4][4];
    const half8* Bp = (const half8*)Bfrag;
    #pragma unroll
    for (int t = 0; t < 4; t++)
        #pragma unroll
        for (int kk = 0; kk < 4; kk++)
            B[t][kk] = Bp[(t*4+kk)*64 + lane];
    float bj[4], lg[4], lb[4];
    #pragma unroll
    for (int t = 0; t < 4; t++){
        int n = t*16 + c;
        bj[t] = b2c[n]; lg[t] = ln_g[n]; lb[t] = ln_b[n];
    }
    int tiles = (N + 15) >> 4;
    int wid = (blockIdx.x*blockDim.x + threadIdx.x) >> 6;
    int nw  = (gridDim.x*blockDim.x) >> 6;
    for (int tile = wid; tile < tiles; tile += nw){
        int nb = tile << 4;
        int anode = nb + c; if (anode >= N) anode = N - 1;
        const half8* ap = (const half8*)(Aj16 + (size_t)anode*64);
        const half8* xp = (const half8*)(xg16 + (size_t)anode*64);
        half8 A0 = ap[q];
        half8 A1 = ap[4 + q];
        half8 A2 = xp[q];
        half8 A3 = xp[4 + q];
        f32x4 acc[4];
        #pragma unroll
        for (int t = 0; t < 4; t++){
            f32x4 z = {0.f, 0.f, 0.f, 0.f};
            z = __builtin_amdgcn_mfma_f32_16x16x32_f16(A0, B[t][0], z, 0, 0, 0);
            z = __builtin_amdgcn_mfma_f32_16x16x32_f16(A1, B[t][1], z, 0, 0, 0);
            z = __builtin_amdgcn_mfma_f32_16x16x32_f16(A2, B[t][2], z, 0, 0, 0);
            z = __builtin_amdgcn_mfma_f32_16x16x32_f16(A3, B[t][3], z, 0, 0, 0);
            acc[t] = z;
        }
        float y[4][4];     // [t][r]
        #pragma unroll
        for (int r = 0; r < 4; r++){
            int node = nb + q*4 + r;
            int nd = node < N ? node : N - 1;
            #pragma unroll
            for (int t = 0; t < 4; t++)
                y[t][r] = acc[t][r] + bj[t]
                        + __half2float(h16[(size_t)nd*64 + t*16 + c]);
        }
        #pragma unroll
        for (int r = 0; r < 4; r++){
            int node = nb + q*4 + r;
            float s = (y[0][r] + y[1][r]) + (y[2][r] + y[3][r]);
            #pragma unroll
            for (int o = 1; o < 16; o <<= 1) s += __shfl_xor(s, o);
            float mu = s * (1.f/64.f);
            float d0 = y[0][r]-mu, d1 = y[1][r]-mu, d2 = y[2][r]-mu, d3 = y[3][r]-mu;
            float var = (d0*d0 + d1*d1) + (d2*d2 + d3*d3);
            #pragma unroll
            for (int o = 1; o < 16; o <<= 1) var += __shfl_xor(var, o);
            var *= (1.f/64.f);
            float rstd = rsqrtf(var + LNEPS);
            if (node < N){
                float dvv = dinv[node];
                #pragma unroll
                for (int t = 0; t < 4; t++){
                    float out = (y[t][r]-mu)*rstd*lg[t] + lb[t];
                    out = out > 0.f ? out : 0.f;
                    h16[(size_t)node*64 + t*16 + c] = __float2half(out);
                    ht16[(size_t)node*64 + t*16 + c] = __float2half(dvv*out);
                }
            }
        }
    }
}

// ---------- readout (h16 input) ----------
__global__ __launch_bounds__(256) void k_readout(const __half* __restrict__ h16,
        const float* __restrict__ W1, const float* __restrict__ b1,
        const float* __restrict__ W2, const float* __restrict__ b2,
        float* __restrict__ out, int N){
    __shared__ float W1t[64*32];
    for (int idx = threadIdx.x; idx < 2048; idx += 256){
        int k = idx >> 5, j = idx & 31;
        W1t[idx] = W1[j*64+k];
    }
    __syncthreads();
    int lane = threadIdx.x & 63;
    float w2  = (lane < 32) ? W2[lane] : 0.f;
    float b1v = (lane < 32) ? b1[lane] : 0.f;
    float b2v = b2[0];
    int wid = (blockIdx.x*blockDim.x + threadIdx.x) >> 6;
    int nw  = (gridDim.x*blockDim.x) >> 6;
    for (int v = wid; v < N; v += nw){
        float hj = __half2float(h16[(size_t)v*64+lane]);
        float acc = b1v;
        #pragma unroll
        for (int k = 0; k < 64; k++){
            float hk = __shfl(hj, k);
            if (lane < 32) acc += hk * W1t[k*32+lane];
        }
        float h1 = acc > 0.f ? acc : 0.f;
        float p = h1 * w2;
        #pragma unroll
        for (int o = 1; o < 32; o <<= 1) p += __shfl_xor(p, o);
        if (lane == 0){
            float z = p + b2v;
            out[v] = 1.f/(1.f + __expf(-z));
        }
    }
}

extern "C" void kernel_launch(void* const* d_in, const int* in_sizes, int n_in,
                              void* d_out, int out_size, void* d_ws, size_t ws_size,
                              hipStream_t stream){
    const ushort_t* xs = (const ushort_t*)d_in[0];
    const int*      ei = (const int*)d_in[1];

    int N = in_sizes[0] / 64;
    int E = in_sizes[1] / 2;
    const int* row = ei;
    const int* col = ei + E;
    int NBK = (N + BWD - 1) / BWD;

    size_t stageF = (size_t)2*E;
    size_t mirF   = (size_t)N*32;
    size_t aliasF = stageF > mirF ? stageF : mirF;

    float* f = (float*)d_ws;
    size_t o = 0;
    int*   flags = (int*)(f + o); o += 16;
    float* P     = f + o; o += P_TOTAL + 63;
    __half* h16  = (__half*)(f + o); o += mirF;
    __half* ht16 = (__half*)(f + o); o += mirF;
    __half* G16  = (__half*)(f + o); o += mirF;
    __half* Aj16 = (__half*)(f + o); size_t aoff = o; o += aliasF;
    __half* xg16 = (__half*)(f + o); size_t xoff = o; o += aliasF;
    uint2* stage_r = (uint2*)(f + aoff);
    uint2* stage_c = (uint2*)(f + xoff);
    float* a_s   = f + o; o += (size_t)N*4;
    float* a_d   = f + o; o += (size_t)N*4;
    float* mxs   = f + o; o += 32;          // 3 layer slots x 8 + pad
    float* dinv  = f + o; o += ((size_t)N + 15) & ~15ull;
    int* bcnt    = (int*)(f + o); o += 512;
    int* bptr_r  = (int*)(f + o); o += 512;
    int* bptr_c  = (int*)(f + o); o += 512;
    int* bcur_r  = (int*)(f + o); o += 512;
    int* bcur_c  = (int*)(f + o); o += 512;
    int* ptr_r   = (int*)(f + o); o += ((size_t)N + 16) & ~15ull;
    int* ptr_c   = (int*)(f + o); o += ((size_t)N + 16) & ~15ull;
    int* re_col  = (int*)(f + o); o += (size_t)E;
    int* ce_row  = (int*)(f + o); o += (size_t)E;
    float* b2c   = f + o; o += 3*64;
    _Float16* Bfrag = (_Float16*)(f + o); o += 3*4096;   // 3*8192 fp16
    _Float16* Bg    = (_Float16*)(f + o); o += 3*2560;   // 3*5120 fp16 (5 t-tiles)

    const float* emb_W   = P + 0;
    const float* emb_b   = P + 4096;
    const float* e8_W    = P + 4160;
    const float* gat_W   = P + 16448;
    const float* att_src = P + 28736;
    const float* att_dst = P + 28928;
    const float* gat_b   = P + 29120;
    const float* fus_W   = P + 29312;
    const float* fus_b   = P + 53888;
    const float* ln_g    = P + 54080;
    const float* ln_b    = P + 54272;
    const float* r_W1    = P + 54464;
    const float* r_b1    = P + 56512;
    const float* r_W2    = P + 56544;
    const float* r_b2    = P + 56576;

    k_init<<<(P_TOTAL+255)/256, 256, 0, stream>>>(
        d_in[2],d_in[3],d_in[4],d_in[5],d_in[6],d_in[7],d_in[8],d_in[9],
        d_in[10],d_in[11],d_in[12],d_in[13],d_in[14],d_in[15],d_in[16],
        d_in[0], flags, P, bcnt, (unsigned*)mxs);

    kb_hist<<<256, 1024, 0, stream>>>(row, col, bcnt, NBK, E);
    kb_scan<<<2, 256, 0, stream>>>(bcnt, bptr_r, bptr_c, bcur_r, bcur_c, NBK, E);
    kb_bin<<<512, 1024, 0, stream>>>(row, col, bcur_r, bcur_c, stage_r, stage_c, NBK, E);
    kb_place<<<2*NBK, 1024, 0, stream>>>(stage_r, stage_c, bptr_r, bptr_c,
                                         ptr_r, ptr_c, re_col, ce_row, dinv, NBK, N, E);

    k_prew_all<<<(PRW_B1+255)/256, 256, 0, stream>>>(fus_W, e8_W, gat_b, fus_b,
                                                     Bfrag, b2c);
    k_prew_bg<<<(3*5120+255)/256, 256, 0, stream>>>(gat_W, att_src, att_dst, Bg);
    k_embed<<<1024, 256, 0, stream>>>(xs, flags, emb_W, emb_b, dinv, h16, ht16, N);

    int ggrid = (N + 31) / 32;
    int tiles = (N + 15) / 16;
    int fgrid = (tiles + 7) / 8;
    k_gat_g<<<fgrid, 256, 0, stream>>>(h16, Bg, G16, a_s, a_d, mxs, N);
    for (int i = 0; i < 3; i++){
        k_gather<<<ggrid, 256, 0, stream>>>(ht16, G16, a_s, a_d, mxs + i*8, dinv,
                                            ptr_r, re_col, ptr_c, ce_row,
                                            Aj16, xg16, N);
        if (i < 2){
            k_fuse_g<<<fgrid, 256, 0, stream>>>(Aj16, xg16, dinv, h16, ht16,
                                                Bfrag + (size_t)i*8192, b2c + i*64,
                                                ln_g + i*64, ln_b + i*64,
                                                Bg + (size_t)(i+1)*5120, G16,
                                                a_s, a_d, mxs + (i+1)*8, N);
        } else {
            k_fuse<<<fgrid, 256, 0, stream>>>(Aj16, xg16, dinv, h16, ht16,
                                              Bfrag + (size_t)i*8192, b2c + i*64,
                                              ln_g + i*64, ln_b + i*64, N);
        }
    }
    k_readout<<<1024, 256, 0, stream>>>(h16, r_W1, r_b1, r_W2, r_b2, (float*)d_out, N);
}

// Round 10
// 651.609 us; speedup vs baseline: 1.3730x; 1.2409x over previous
//
#include <hip/hip_runtime.h>
#include <hip/hip_bf16.h>
#include <hip/hip_fp16.h>

typedef __hip_bfloat16 bf16;
typedef unsigned short ushort_t;
typedef unsigned short us8 __attribute__((ext_vector_type(8)));
typedef _Float16 half8 __attribute__((ext_vector_type(8)));
typedef float f32x4 __attribute__((ext_vector_type(4)));

#define NEG 0.2f
#define LNEPS 1e-5f
#define BWD 512                 // CSR bucket width (nodes)

__device__ __forceinline__ int plaus(unsigned int lo){
    lo &= 0x7FFFu;
    if (lo == 0) return 1;
    unsigned int ex = (lo >> 7) & 0xFF;
    return (ex >= 100 && ex <= 140) ? 1 : 0;
}

__device__ __forceinline__ float decode_slot(const ushort_t* s, long long i, int fl){
    long long base = i << fl;
    unsigned int hi = s[base + fl];
    unsigned int lo = s[base];
    unsigned int bits = (hi << 16) | (lo * (unsigned int)fl);
    return __uint_as_float(bits);
}

// order-preserving float<->uint encoding for atomicMax on floats (incl. negatives)
__device__ __forceinline__ unsigned encf(float f){
    int b = __float_as_int(f);
    return (b >= 0) ? ((unsigned)b | 0x80000000u) : (unsigned)(~b);
}
__device__ __forceinline__ float decf(unsigned k){
    return (k & 0x80000000u) ? __uint_as_float(k & 0x7FFFFFFFu)
                             : __uint_as_float(~k);
}

// ---------- init: param convert (inline detect) + flags + mxs + edge histogram ----------
// blocks 0..CONV-1: param convert (block 0 also flags/mxs; bcnt zeroed by prior memset)
// blocks CONV..CONV+255: per-block LDS histogram of row/col buckets -> atomicAdd bcnt
#define P_TOTAL 56577
#define CONV_BLKS 222
__global__ __launch_bounds__(256) void k_init(const void* p0, const void* p1, const void* p2,
        const void* p3, const void* p4, const void* p5, const void* p6, const void* p7,
        const void* p8, const void* p9, const void* p10, const void* p11, const void* p12,
        const void* p13, const void* p14, const void* xs,
        const int* __restrict__ row, const int* __restrict__ col, int E, int NBK,
        int* flags, float* P, int* bcnt, unsigned* mxsu){
    __shared__ int lh[512];
    int t = threadIdx.x;
    if (blockIdx.x >= CONV_BLKS){
        int hb = blockIdx.x - CONV_BLKS;
        for (int i = t; i < 2*NBK; i += 256) lh[i] = 0;
        __syncthreads();
        for (long long e = (long long)hb*256 + t; e < E; e += (long long)256*256){
            atomicAdd(&lh[row[e] >> 9], 1);
            atomicAdd(&lh[NBK + (col[e] >> 9)], 1);
        }
        __syncthreads();
        for (int i = t; i < 2*NBK; i += 256){
            int v = lh[i];
            if (v) atomicAdd(&bcnt[i], v);
        }
        return;
    }
    if (blockIdx.x == 0){
        if (t < 9){
            const void* dt[9] = {xs, p0, p2, p3, p4, p5, p7, p11, p13};
            const ushort_t* w = (const ushort_t*)dt[t];
            int all_bf = 1;
            for (int i = 0; i < 16; i++) all_bf &= plaus((unsigned int)w[i]);
            flags[t] = all_bf ? 0 : 1;
        } else if (t == 9){
            const ushort_t* w = (const ushort_t*)p9;
            flags[9] = (w[0] == 0x3F80u) ? 0 : 1;
        }
        if (t < 32) mxsu[t] = 0u;            // encoded -inf for 3 layer slots
    }
    int idx = blockIdx.x*256 + t;
    if (idx >= P_TOTAL) return;
    const int sizes[15] = {4096,64,12288,12288,192,192,192,24576,192,192,192,2048,32,32,1};
    const int fidx[15]  = {1,  -1,  2,    3,    4,  5,  -1, 6,    -1, 9,  -1, 7,   -1,8, -1};
    const void* ptrs[15] = {p0,p1,p2,p3,p4,p5,p6,p7,p8,p9,p10,p11,p12,p13,p14};
    int s = 0, base = 0;
    while (idx - base >= sizes[s]){ base += sizes[s]; s++; }
    int li = idx - base;
    int fi = fidx[s];
    int fl = 0;
    if (fi == 9){
        const ushort_t* w = (const ushort_t*)ptrs[s];
        fl = (w[0] == 0x3F80u) ? 0 : 1;
    } else if (fi >= 0){
        const ushort_t* w = (const ushort_t*)ptrs[s];
        int all_bf = 1;
        for (int i = 0; i < 16; i++) all_bf &= plaus((unsigned int)w[i]);
        fl = all_bf ? 0 : 1;
    }
    P[idx] = decode_slot((const ushort_t*)ptrs[s], li, fl);
}

// ---------- scan + weight precompute, one launch (block-role split) ----------
// blocks 0,1: bucket exclusive scan (side = blockIdx). blocks 2..: Bfrag/b2c/Bg build.
#define PRW_B0 (3*8192)
#define PRW_B1 (PRW_B0 + 192)
#define PRW_B2 (PRW_B1 + 3*5120)
__global__ __launch_bounds__(256) void kb_scanprew(const int* __restrict__ bcnt,
        int* __restrict__ bptr_r, int* __restrict__ bptr_c,
        int* __restrict__ bcur_r, int* __restrict__ bcur_c, int NBK, int E,
        const float* __restrict__ fus_W, const float* __restrict__ e8_W,
        const float* __restrict__ gat_b, const float* __restrict__ fus_b,
        const float* __restrict__ gat_W, const float* __restrict__ att_src,
        const float* __restrict__ att_dst,
        _Float16* __restrict__ Bfrag, float* __restrict__ b2c, _Float16* __restrict__ Bg){
    __shared__ int sh[256];
    int t = threadIdx.x;
    if (blockIdx.x < 2){
        int side = blockIdx.x;
        const int* c = bcnt + side*NBK;
        int* bp = side ? bptr_c : bptr_r;
        int* bc = side ? bcur_c : bcur_r;
        int v = (t < NBK) ? c[t] : 0;
        sh[t] = v; __syncthreads();
        for (int off = 1; off < 256; off <<= 1){
            int add = (t >= off) ? sh[t-off] : 0;
            __syncthreads();
            sh[t] += add;
            __syncthreads();
        }
        if (t < NBK){ int e = sh[t] - v; bp[t] = e; bc[t] = e; }
        if (t == 0) bp[NBK] = E;
        return;
    }
    int idx = (blockIdx.x - 2)*256 + t;
    if (idx < PRW_B0){
        int i = idx / 8192; int rem = idx & 8191;
        int j = rem & 7, lane = (rem >> 3) & 63, kk = (rem >> 9) & 3, tt = rem >> 11;
        int k = kk*32 + (lane >> 4)*8 + j;
        int n = tt*16 + (lane & 15);
        float v;
        if (k < 64){
            const float* fw = fus_W + (size_t)i*8192 + (size_t)n*128;
            const float* ew = e8_W + (size_t)i*4096;
            float acc = 0.f;
            for (int p = 0; p < 64; p++) acc += fw[p] * ew[p*64 + k];
            v = acc;
        } else {
            v = fus_W[(size_t)i*8192 + (size_t)n*128 + 64 + (k - 64)];
        }
        Bfrag[idx] = (_Float16)v;
    } else if (idx < PRW_B1){
        int t2 = idx - PRW_B0;
        int i = t2 >> 6, j = t2 & 63;
        const float* fw = fus_W + (size_t)i*8192 + (size_t)j*128 + 64;
        float acc = fus_b[i*64+j];
        for (int p = 0; p < 64; p++) acc += gat_b[i*64+p] * fw[p];
        b2c[t2] = acc;
    } else if (idx < PRW_B2){
        int t3 = idx - PRW_B1;
        int i = t3 / 5120; int rem = t3 % 5120;
        int j = rem & 7, lane = (rem >> 3) & 63, kk = (rem >> 9) & 1, tt = rem >> 10;
        int k = kk*32 + (lane >> 4)*8 + j;
        int nn = lane & 15;
        float v;
        if (tt < 4){
            v = gat_W[(size_t)i*4096 + k*64 + (tt*16 + nn)];
        } else if (nn < 8){
            int hx = nn >> 1;
            const float* att = (nn & 1) ? att_dst : att_src;
            float acc = 0.f;
            for (int cc = 0; cc < 16; cc++)
                acc += gat_W[(size_t)i*4096 + k*64 + hx*16 + cc] * att[i*64 + hx*16 + cc];
            v = acc;
        } else {
            v = 0.f;
        }
        Bg[t3] = (_Float16)v;
    }
}

// both sides in one launch: blocks 0..255 row-keyed, 256..511 col-keyed
__global__ __launch_bounds__(1024) void kb_bin(const int* __restrict__ row,
        const int* __restrict__ col, int* __restrict__ bcur_r, int* __restrict__ bcur_c,
        uint2* __restrict__ stage_r, uint2* __restrict__ stage_c, int NBK, int E){
    __shared__ int lh[256], lbase[256];
    int side = blockIdx.x >> 8;
    int bid  = blockIdx.x & 255;
    const int* key = side ? col : row;
    const int* pay = side ? row : col;
    int* bcur = side ? bcur_c : bcur_r;
    uint2* stage = side ? stage_c : stage_r;
    int t = threadIdx.x;
    for (long long tile = (long long)bid*1024; tile < E; tile += (long long)256*1024){
        for (int i = t; i < NBK; i += 1024) lh[i] = 0;
        __syncthreads();
        int e = (int)tile + t;
        int k = 0, p = 0, b = -1, rank = 0;
        if (e < E){
            k = key[e]; p = pay[e]; b = k >> 9;
            rank = atomicAdd(&lh[b], 1);
        }
        __syncthreads();
        for (int i = t; i < NBK; i += 1024){
            int c = lh[i];
            lbase[i] = c ? atomicAdd(&bcur[i], c) : 0;
        }
        __syncthreads();
        if (b >= 0) stage[lbase[b] + rank] = make_uint2((unsigned)k, (unsigned)p);
        __syncthreads();
    }
}

// both sides in one launch: blocks 0..NBK-1 row, NBK..2NBK-1 col
__global__ __launch_bounds__(1024) void kb_place(const uint2* __restrict__ stage_r,
        const uint2* __restrict__ stage_c, const int* __restrict__ bptr_r,
        const int* __restrict__ bptr_c, int* __restrict__ ptr_r, int* __restrict__ ptr_c,
        int* __restrict__ re_col, int* __restrict__ ce_row,
        float* __restrict__ dinv, int NBK, int N, int E){
    __shared__ int lcnt[BWD], lsc[BWD], lcur[BWD];
    int side = blockIdx.x >= NBK;
    int b = blockIdx.x - (side ? NBK : 0);
    const uint2* stage = side ? stage_c : stage_r;
    const int* bptr = side ? bptr_c : bptr_r;
    int* ptr = side ? ptr_c : ptr_r;
    int* outarr = side ? ce_row : re_col;
    int wantdinv = side;
    int s = bptr[b], e = bptr[b+1];
    int nbase = b << 9;
    int t = threadIdx.x;
    if (t < BWD) lcnt[t] = 0;
    __syncthreads();
    for (int i = s + t; i < e; i += 1024)
        atomicAdd(&lcnt[stage[i].x - nbase], 1);
    __syncthreads();
    if (t < BWD) lsc[t] = lcnt[t];
    __syncthreads();
    for (int off = 1; off < BWD; off <<= 1){
        int add = (t >= off && t < BWD) ? lsc[t-off] : 0;
        __syncthreads();
        if (t < BWD) lsc[t] += add;
        __syncthreads();
    }
    if (t < BWD){
        int node = nbase + t;
        int excl = lsc[t] - lcnt[t];
        lcur[t] = excl;
        if (node < N){
            ptr[node] = s + excl;
            if (wantdinv) dinv[node] = lcnt[t] > 0 ? rsqrtf((float)lcnt[t]) : 0.f;
        }
    }
    if (b == 0 && t == 0) ptr[N] = E;
    __syncthreads();
    for (int i = s + t; i < e; i += 1024){
        uint2 rec = stage[i];
        int pos = s + atomicAdd(&lcur[rec.x - nbase], 1);
        outarr[pos] = (int)rec.y;
    }
}

// ---------- embed + layer-0 G projection (MFMA embed, tbuf transpose, G MFMAs) ----------
__global__ __launch_bounds__(256) void k_embed_g(const ushort_t* __restrict__ xs,
        const int* __restrict__ flags, const float* __restrict__ W,
        const float* __restrict__ b, const float* __restrict__ dinv,
        const _Float16* __restrict__ Bgn,
        __half* __restrict__ h16, __half* __restrict__ ht16, __half* __restrict__ G16,
        float* __restrict__ a_s, float* __restrict__ a_d, float* __restrict__ mxs, int N){
    __shared__ float redm[4][8];
    __shared__ _Float16 tbuf[4][1024];
    int lane = threadIdx.x & 63;
    int wv = threadIdx.x >> 6;
    int q = lane >> 4, c = lane & 15;
    _Float16* tb = tbuf[wv];
    int fl = flags[0];
    // emb_W B-frags: Be[t][kk][j] = W[n*64+k], n=t*16+c, k=kk*32+q*8+j
    half8 Be[4][2];
    #pragma unroll
    for (int t = 0; t < 4; t++){
        #pragma unroll
        for (int kk = 0; kk < 2; kk++){
            half8 v;
            #pragma unroll
            for (int j = 0; j < 8; j++)
                v[j] = (_Float16)W[(t*16 + c)*64 + kk*32 + q*8 + j];
            Be[t][kk] = v;
        }
    }
    half8 Bg[5][2];
    const half8* Bgp = (const half8*)Bgn;
    #pragma unroll
    for (int t = 0; t < 5; t++)
        #pragma unroll
        for (int kk = 0; kk < 2; kk++)
            Bg[t][kk] = Bgp[(t*2+kk)*64 + lane];
    float bj[4];
    #pragma unroll
    for (int t = 0; t < 4; t++) bj[t] = b[t*16 + c];
    float lmax = -1e30f;
    int tiles = (N + 15) >> 4;
    int wid = (blockIdx.x*blockDim.x + threadIdx.x) >> 6;
    int nw  = (gridDim.x*blockDim.x) >> 6;
    for (int tile = wid; tile < tiles; tile += nw){
        int nb = tile << 4;
        int anode = nb + c; if (anode >= N) anode = N - 1;
        half8 A0, A1;
        #pragma unroll
        for (int j = 0; j < 8; j++){
            A0[j] = (_Float16)decode_slot(xs, (long long)anode*64 + q*8 + j, fl);
            A1[j] = (_Float16)decode_slot(xs, (long long)anode*64 + 32 + q*8 + j, fl);
        }
        f32x4 acc[4];
        #pragma unroll
        for (int t = 0; t < 4; t++){
            f32x4 z = {0.f, 0.f, 0.f, 0.f};
            z = __builtin_amdgcn_mfma_f32_16x16x32_f16(A0, Be[t][0], z, 0, 0, 0);
            z = __builtin_amdgcn_mfma_f32_16x16x32_f16(A1, Be[t][1], z, 0, 0, 0);
            acc[t] = z;
        }
        #pragma unroll
        for (int r = 0; r < 4; r++){
            int node = nb + q*4 + r;
            int nd2 = q*4 + r;
            #pragma unroll
            for (int t = 0; t < 4; t++){
                float out = acc[t][r] + bj[t];
                int byte = nd2*128 + (t*16 + c)*2;
                byte ^= (nd2 & 7) << 4;
                *(_Float16*)((char*)tb + byte) = (_Float16)out;
                if (node < N){
                    h16[(size_t)node*64 + t*16 + c] = __float2half(out);
                    ht16[(size_t)node*64 + t*16 + c] = __float2half(dinv[node]*out);
                }
            }
        }
        int b0 = (c*128 + 16*q) ^ ((c & 7) << 4);
        int b1 = (c*128 + 64 + 16*q) ^ ((c & 7) << 4);
        half8 A0g = *(half8*)((char*)tb + b0);
        half8 A1g = *(half8*)((char*)tb + b1);
        f32x4 gacc[5];
        #pragma unroll
        for (int t = 0; t < 5; t++){
            f32x4 z = {0.f, 0.f, 0.f, 0.f};
            z = __builtin_amdgcn_mfma_f32_16x16x32_f16(A0g, Bg[t][0], z, 0, 0, 0);
            z = __builtin_amdgcn_mfma_f32_16x16x32_f16(A1g, Bg[t][1], z, 0, 0, 0);
            gacc[t] = z;
        }
        #pragma unroll
        for (int r = 0; r < 4; r++) lmax = fmaxf(lmax, gacc[4][r]);
        #pragma unroll
        for (int r = 0; r < 4; r++){
            int node = nb + q*4 + r;
            if (node < N){
                #pragma unroll
                for (int t = 0; t < 4; t++)
                    G16[(size_t)node*64 + t*16 + c] = __float2half(gacc[t][r]);
                if (c < 8){
                    int hx = c >> 1;
                    if (c & 1) a_d[node*4+hx] = gacc[4][r];
                    else       a_s[node*4+hx] = gacc[4][r];
                }
            }
        }
    }
    lmax = fmaxf(lmax, __shfl_xor(lmax, 16));
    lmax = fmaxf(lmax, __shfl_xor(lmax, 32));
    if (lane < 8) redm[wv][lane] = lmax;
    __syncthreads();
    if (threadIdx.x < 8){
        float m = fmaxf(fmaxf(redm[0][threadIdx.x], redm[1][threadIdx.x]),
                        fmaxf(redm[2][threadIdx.x], redm[3][threadIdx.x]));
        int hx = threadIdx.x >> 1;
        int ix = (threadIdx.x & 1) ? 4 + hx : hx;
        atomicMax((unsigned*)mxs + ix, encf(m));
    }
}

__device__ __forceinline__ float leaky(float t){ return t > 0.f ? t : NEG*t; }

// ---------- gather: 8 nodes/wave, 8 lanes/node, 16B loads (round-6 proven form) ----------
__global__ __launch_bounds__(256) void k_gather(const __half* __restrict__ ht16,
        const __half* __restrict__ G16,
        const float* __restrict__ a_s, const float* __restrict__ a_d,
        const float* __restrict__ mxs, const float* __restrict__ dinv,
        const int* __restrict__ row_ptr, const int* __restrict__ re_col,
        const int* __restrict__ col_ptr, const int* __restrict__ ce_row,
        __half* __restrict__ Aj16, __half* __restrict__ xg16, int N){
    int lane = threadIdx.x & 63;
    int grp  = lane >> 3;
    int sub  = lane & 7;
    int hh   = sub >> 1;
    int wid  = (blockIdx.x*blockDim.x + threadIdx.x) >> 6;
    int v    = wid*8 + grp;
    if (v >= N) return;
    const us8* htb = (const us8*)ht16;
    const us8* gb  = (const us8*)G16;
    const unsigned* mu = (const unsigned*)mxs;
    float sh = leaky(decf(mu[hh]) + decf(mu[4+hh]));
    int rs = row_ptr[v], re = row_ptr[v+1];
    float a0[8] = {0,0,0,0,0,0,0,0}, a1[8] = {0,0,0,0,0,0,0,0};
    float a2[8] = {0,0,0,0,0,0,0,0}, a3[8] = {0,0,0,0,0,0,0,0};
    int i = rs;
    for (; i + 3 < re; i += 4){
        us8 q0 = htb[(size_t)re_col[i]*8 + sub];
        us8 q1 = htb[(size_t)re_col[i+1]*8 + sub];
        us8 q2 = htb[(size_t)re_col[i+2]*8 + sub];
        us8 q3 = htb[(size_t)re_col[i+3]*8 + sub];
        #pragma unroll
        for (int j = 0; j < 8; j++){
            a0[j] += __half2float(__ushort_as_half(q0[j]));
            a1[j] += __half2float(__ushort_as_half(q1[j]));
            a2[j] += __half2float(__ushort_as_half(q2[j]));
            a3[j] += __half2float(__ushort_as_half(q3[j]));
        }
    }
    for (; i < re; i++){
        us8 q0 = htb[(size_t)re_col[i]*8 + sub];
        #pragma unroll
        for (int j = 0; j < 8; j++) a0[j] += __half2float(__ushort_as_half(q0[j]));
    }
    float dv = dinv[v];
    us8 pa;
    #pragma unroll
    for (int j = 0; j < 8; j++)
        pa[j] = __half_as_ushort(__float2half(dv*((a0[j]+a1[j]) + (a2[j]+a3[j]))));
    ((us8*)Aj16)[(size_t)v*8 + sub] = pa;
    float adv = a_d[v*4+hh];
    float eesl = __expf(leaky(a_s[v*4+hh] + adv) - sh);
    float s0 = eesl, s1 = 0.f, s2 = 0.f, s3 = 0.f;
    {
        us8 g0 = gb[(size_t)v*8 + sub];
        #pragma unroll
        for (int j = 0; j < 8; j++){
            a0[j] = eesl * __half2float(__ushort_as_half(g0[j]));
            a1[j] = 0.f; a2[j] = 0.f; a3[j] = 0.f;
        }
    }
    int cs = col_ptr[v], ce = col_ptr[v+1];
    i = cs;
    for (; i + 3 < ce; i += 4){
        int r0 = ce_row[i], r1 = ce_row[i+1], r2 = ce_row[i+2], r3 = ce_row[i+3];
        float e0 = __expf(leaky(a_s[r0*4+hh] + adv) - sh);
        float e1 = __expf(leaky(a_s[r1*4+hh] + adv) - sh);
        float e2 = __expf(leaky(a_s[r2*4+hh] + adv) - sh);
        float e3 = __expf(leaky(a_s[r3*4+hh] + adv) - sh);
        us8 q0 = gb[(size_t)r0*8 + sub];
        us8 q1 = gb[(size_t)r1*8 + sub];
        us8 q2 = gb[(size_t)r2*8 + sub];
        us8 q3 = gb[(size_t)r3*8 + sub];
        #pragma unroll
        for (int j = 0; j < 8; j++){
            a0[j] += e0 * __half2float(__ushort_as_half(q0[j]));
            a1[j] += e1 * __half2float(__ushort_as_half(q1[j]));
            a2[j] += e2 * __half2float(__ushort_as_half(q2[j]));
            a3[j] += e3 * __half2float(__ushort_as_half(q3[j]));
        }
        s0 += e0; s1 += e1; s2 += e2; s3 += e3;
    }
    for (; i < ce; i++){
        int r0 = ce_row[i];
        float e0 = __expf(leaky(a_s[r0*4+hh] + adv) - sh);
        us8 q0 = gb[(size_t)r0*8 + sub];
        #pragma unroll
        for (int j = 0; j < 8; j++) a0[j] += e0 * __half2float(__ushort_as_half(q0[j]));
        s0 += e0;
    }
    float inv = 1.f/((s0+s1)+(s2+s3));
    us8 px;
    #pragma unroll
    for (int j = 0; j < 8; j++)
        px[j] = __half_as_ushort(__float2half(((a0[j]+a1[j]) + (a2[j]+a3[j]))*inv));
    ((us8*)xg16)[(size_t)v*8 + sub] = px;
}

// ---------- fuse+G (layers 0,1): fusion epilogue + NEXT layer's G via LDS transpose ----------
__global__ __launch_bounds__(256) void k_fuse_g(
        const __half* __restrict__ Aj16, const __half* __restrict__ xg16,
        const float* __restrict__ dinv, __half* __restrict__ h16,
        __half* __restrict__ ht16,
        const _Float16* __restrict__ Bfrag, const float* __restrict__ b2c,
        const float* __restrict__ ln_g, const float* __restrict__ ln_b,
        const _Float16* __restrict__ Bgn, __half* __restrict__ G16,
        float* __restrict__ a_s, float* __restrict__ a_d,
        float* __restrict__ mxs_next, int N){
    __shared__ float redm[4][8];
    __shared__ _Float16 tbuf[4][1024];
    int lane = threadIdx.x & 63;
    int wv = threadIdx.x >> 6;
    int q = lane >> 4, c = lane & 15;
    _Float16* tb = tbuf[wv];
    half8 B[4][4];
    const half8* Bp = (const half8*)Bfrag;
    #pragma unroll
    for (int t = 0; t < 4; t++)
        #pragma unroll
        for (int kk = 0; kk < 4; kk++)
            B[t][kk] = Bp[(t*4+kk)*64 + lane];
    half8 Bg[5][2];
    const half8* Bgp = (const half8*)Bgn;
    #pragma unroll
    for (int t = 0; t < 5; t++)
        #pragma unroll
        for (int kk = 0; kk < 2; kk++)
            Bg[t][kk] = Bgp[(t*2+kk)*64 + lane];
    float bj[4], lg[4], lb[4];
    #pragma unroll
    for (int t = 0; t < 4; t++){
        int n = t*16 + c;
        bj[t] = b2c[n]; lg[t] = ln_g[n]; lb[t] = ln_b[n];
    }
    float lmax = -1e30f;
    int tiles = (N + 15) >> 4;
    int wid = (blockIdx.x*blockDim.x + threadIdx.x) >> 6;
    int nw  = (gridDim.x*blockDim.x) >> 6;
    for (int tile = wid; tile < tiles; tile += nw){
        int nb = tile << 4;
        int anode = nb + c; if (anode >= N) anode = N - 1;
        const half8* ap = (const half8*)(Aj16 + (size_t)anode*64);
        const half8* xp = (const half8*)(xg16 + (size_t)anode*64);
        half8 A0 = ap[q];
        half8 A1 = ap[4 + q];
        half8 A2 = xp[q];
        half8 A3 = xp[4 + q];
        f32x4 acc[4];
        #pragma unroll
        for (int t = 0; t < 4; t++){
            f32x4 z = {0.f, 0.f, 0.f, 0.f};
            z = __builtin_amdgcn_mfma_f32_16x16x32_f16(A0, B[t][0], z, 0, 0, 0);
            z = __builtin_amdgcn_mfma_f32_16x16x32_f16(A1, B[t][1], z, 0, 0, 0);
            z = __builtin_amdgcn_mfma_f32_16x16x32_f16(A2, B[t][2], z, 0, 0, 0);
            z = __builtin_amdgcn_mfma_f32_16x16x32_f16(A3, B[t][3], z, 0, 0, 0);
            acc[t] = z;
        }
        float y[4][4];     // [t][r]
        #pragma unroll
        for (int r = 0; r < 4; r++){
            int node = nb + q*4 + r;
            int nd = node < N ? node : N - 1;
            #pragma unroll
            for (int t = 0; t < 4; t++)
                y[t][r] = acc[t][r] + bj[t]
                        + __half2float(h16[(size_t)nd*64 + t*16 + c]);
        }
        #pragma unroll
        for (int r = 0; r < 4; r++){
            int node = nb + q*4 + r;
            float s = (y[0][r] + y[1][r]) + (y[2][r] + y[3][r]);
            #pragma unroll
            for (int o = 1; o < 16; o <<= 1) s += __shfl_xor(s, o);
            float mu = s * (1.f/64.f);
            float d0 = y[0][r]-mu, d1 = y[1][r]-mu, d2 = y[2][r]-mu, d3 = y[3][r]-mu;
            float var = (d0*d0 + d1*d1) + (d2*d2 + d3*d3);
            #pragma unroll
            for (int o = 1; o < 16; o <<= 1) var += __shfl_xor(var, o);
            var *= (1.f/64.f);
            float rstd = rsqrtf(var + LNEPS);
            int nd2 = q*4 + r;
            #pragma unroll
            for (int t = 0; t < 4; t++){
                float out = (y[t][r]-mu)*rstd*lg[t] + lb[t];
                out = out > 0.f ? out : 0.f;
                int byte = nd2*128 + (t*16 + c)*2;
                byte ^= (nd2 & 7) << 4;
                *(_Float16*)((char*)tb + byte) = (_Float16)out;
                if (node < N){
                    h16[(size_t)node*64 + t*16 + c] = __float2half(out);
                    ht16[(size_t)node*64 + t*16 + c] = __float2half(dinv[node]*out);
                }
            }
        }
        int b0 = (c*128 + 16*q) ^ ((c & 7) << 4);
        int b1 = (c*128 + 64 + 16*q) ^ ((c & 7) << 4);
        half8 A0g = *(half8*)((char*)tb + b0);
        half8 A1g = *(half8*)((char*)tb + b1);
        f32x4 gacc[5];
        #pragma unroll
        for (int t = 0; t < 5; t++){
            f32x4 z = {0.f, 0.f, 0.f, 0.f};
            z = __builtin_amdgcn_mfma_f32_16x16x32_f16(A0g, Bg[t][0], z, 0, 0, 0);
            z = __builtin_amdgcn_mfma_f32_16x16x32_f16(A1g, Bg[t][1], z, 0, 0, 0);
            gacc[t] = z;
        }
        #pragma unroll
        for (int r = 0; r < 4; r++) lmax = fmaxf(lmax, gacc[4][r]);
        #pragma unroll
        for (int r = 0; r < 4; r++){
            int node = nb + q*4 + r;
            if (node < N){
                #pragma unroll
                for (int t = 0; t < 4; t++)
                    G16[(size_t)node*64 + t*16 + c] = __float2half(gacc[t][r]);
                if (c < 8){
                    int hx = c >> 1;
                    if (c & 1) a_d[node*4+hx] = gacc[4][r];
                    else       a_s[node*4+hx] = gacc[4][r];
                }
            }
        }
    }
    lmax = fmaxf(lmax, __shfl_xor(lmax, 16));
    lmax = fmaxf(lmax, __shfl_xor(lmax, 32));
    if (lane < 8) redm[wv][lane] = lmax;
    __syncthreads();
    if (threadIdx.x < 8){
        float m = fmaxf(fmaxf(redm[0][threadIdx.x], redm[1][threadIdx.x]),
                        fmaxf(redm[2][threadIdx.x], redm[3][threadIdx.x]));
        int hx = threadIdx.x >> 1;
        int ix = (threadIdx.x & 1) ? 4 + hx : hx;
        atomicMax((unsigned*)mxs_next + ix, encf(m));
    }
}

// ---------- fuse layer 2 + readout (tbuf transpose -> r_W1 MFMA -> w2 dot -> sigmoid) ----
// h16/ht16 are dead after this layer: no hidden-state writes at all.
__global__ __launch_bounds__(256) void k_fuse_ro(
        const __half* __restrict__ Aj16, const __half* __restrict__ xg16,
        const __half* __restrict__ h16,
        const _Float16* __restrict__ Bfrag, const float* __restrict__ b2c,
        const float* __restrict__ ln_g, const float* __restrict__ ln_b,
        const float* __restrict__ rW1, const float* __restrict__ rb1,
        const float* __restrict__ rW2, const float* __restrict__ rb2,
        float* __restrict__ out, int N){
    __shared__ _Float16 tbuf[4][1024];
    int lane = threadIdx.x & 63;
    int wv = threadIdx.x >> 6;
    int q = lane >> 4, c = lane & 15;
    _Float16* tb = tbuf[wv];
    half8 B[4][4];
    const half8* Bp = (const half8*)Bfrag;
    #pragma unroll
    for (int t = 0; t < 4; t++)
        #pragma unroll
        for (int kk = 0; kk < 4; kk++)
            B[t][kk] = Bp[(t*4+kk)*64 + lane];
    // r_W1 B-frags: B1r[t][kk][j] = rW1[n*64+k], n=t*16+c (n<32), k=kk*32+q*8+j
    half8 B1r[2][2];
    #pragma unroll
    for (int t = 0; t < 2; t++){
        #pragma unroll
        for (int kk = 0; kk < 2; kk++){
            half8 v;
            #pragma unroll
            for (int j = 0; j < 8; j++)
                v[j] = (_Float16)rW1[(t*16 + c)*64 + kk*32 + q*8 + j];
            B1r[t][kk] = v;
        }
    }
    float bj[4], lg[4], lb[4];
    #pragma unroll
    for (int t = 0; t < 4; t++){
        int n = t*16 + c;
        bj[t] = b2c[n]; lg[t] = ln_g[n]; lb[t] = ln_b[n];
    }
    float b1v[2] = {rb1[c], rb1[16 + c]};
    float w2a = rW2[c], w2b = rW2[16 + c];
    float b2v = rb2[0];
    int tiles = (N + 15) >> 4;
    int wid = (blockIdx.x*blockDim.x + threadIdx.x) >> 6;
    int nw  = (gridDim.x*blockDim.x) >> 6;
    for (int tile = wid; tile < tiles; tile += nw){
        int nb = tile << 4;
        int anode = nb + c; if (anode >= N) anode = N - 1;
        const half8* ap = (const half8*)(Aj16 + (size_t)anode*64);
        const half8* xp = (const half8*)(xg16 + (size_t)anode*64);
        half8 A0 = ap[q];
        half8 A1 = ap[4 + q];
        half8 A2 = xp[q];
        half8 A3 = xp[4 + q];
        f32x4 acc[4];
        #pragma unroll
        for (int t = 0; t < 4; t++){
            f32x4 z = {0.f, 0.f, 0.f, 0.f};
            z = __builtin_amdgcn_mfma_f32_16x16x32_f16(A0, B[t][0], z, 0, 0, 0);
            z = __builtin_amdgcn_mfma_f32_16x16x32_f16(A1, B[t][1], z, 0, 0, 0);
            z = __builtin_amdgcn_mfma_f32_16x16x32_f16(A2, B[t][2], z, 0, 0, 0);
            z = __builtin_amdgcn_mfma_f32_16x16x32_f16(A3, B[t][3], z, 0, 0, 0);
            acc[t] = z;
        }
        float y[4][4];     // [t][r]
        #pragma unroll
        for (int r = 0; r < 4; r++){
            int node = nb + q*4 + r;
            int nd = node < N ? node : N - 1;
            #pragma unroll
            for (int t = 0; t < 4; t++)
                y[t][r] = acc[t][r] + bj[t]
                        + __half2float(h16[(size_t)nd*64 + t*16 + c]);
        }
        #pragma unroll
        for (int r = 0; r < 4; r++){
            float s = (y[0][r] + y[1][r]) + (y[2][r] + y[3][r]);
            #pragma unroll
            for (int o = 1; o < 16; o <<= 1) s += __shfl_xor(s, o);
            float mu = s * (1.f/64.f);
            float d0 = y[0][r]-mu, d1 = y[1][r]-mu, d2 = y[2][r]-mu, d3 = y[3][r]-mu;
            float var = (d0*d0 + d1*d1) + (d2*d2 + d3*d3);
            #pragma unroll
            for (int o = 1; o < 16; o <<= 1) var += __shfl_xor(var, o);
            var *= (1.f/64.f);
            float rstd = rsqrtf(var + LNEPS);
            int nd2 = q*4 + r;
            #pragma unroll
            for (int t = 0; t < 4; t++){
                float outv = (y[t][r]-mu)*rstd*lg[t] + lb[t];
                outv = outv > 0.f ? outv : 0.f;
                int byte = nd2*128 + (t*16 + c)*2;
                byte ^= (nd2 & 7) << 4;
                *(_Float16*)((char*)tb + byte) = (_Float16)outv;
            }
        }
        int b0 = (c*128 + 16*q) ^ ((c & 7) << 4);
        int b1 = (c*128 + 64 + 16*q) ^ ((c & 7) << 4);
        half8 A0g = *(half8*)((char*)tb + b0);
        half8 A1g = *(half8*)((char*)tb + b1);
        f32x4 racc[2];
        #pragma unroll
        for (int t = 0; t < 2; t++){
            f32x4 z = {0.f, 0.f, 0.f, 0.f};
            z = __builtin_amdgcn_mfma_f32_16x16x32_f16(A0g, B1r[t][0], z, 0, 0, 0);
            z = __builtin_amdgcn_mfma_f32_16x16x32_f16(A1g, B1r[t][1], z, 0, 0, 0);
            racc[t] = z;
        }
        #pragma unroll
        for (int r = 0; r < 4; r++){
            int node = nb + q*4 + r;
            float h1a = racc[0][r] + b1v[0]; h1a = h1a > 0.f ? h1a : 0.f;
            float h1b = racc[1][r] + b1v[1]; h1b = h1b > 0.f ? h1b : 0.f;
            float p = h1a*w2a + h1b*w2b;
            p += __shfl_xor(p, 1);
            p += __shfl_xor(p, 2);
            p += __shfl_xor(p, 4);
            p += __shfl_xor(p, 8);
            if (c == 0 && node < N){
                float z = p + b2v;
                out[node] = 1.f/(1.f + __expf(-z));
            }
        }
    }
}

extern "C" void kernel_launch(void* const* d_in, const int* in_sizes, int n_in,
                              void* d_out, int out_size, void* d_ws, size_t ws_size,
                              hipStream_t stream){
    const ushort_t* xs = (const ushort_t*)d_in[0];
    const int*      ei = (const int*)d_in[1];

    int N = in_sizes[0] / 64;
    int E = in_sizes[1] / 2;
    const int* row = ei;
    const int* col = ei + E;
    int NBK = (N + BWD - 1) / BWD;

    size_t stageF = (size_t)2*E;
    size_t mirF   = (size_t)N*32;
    size_t aliasF = stageF > mirF ? stageF : mirF;

    float* f = (float*)d_ws;
    size_t o = 0;
    int*   flags = (int*)(f + o); o += 16;
    float* P     = f + o; o += P_TOTAL + 63;
    __half* h16  = (__half*)(f + o); o += mirF;
    __half* ht16 = (__half*)(f + o); o += mirF;
    __half* G16  = (__half*)(f + o); o += mirF;
    __half* Aj16 = (__half*)(f + o); size_t aoff = o; o += aliasF;
    __half* xg16 = (__half*)(f + o); size_t xoff = o; o += aliasF;
    uint2* stage_r = (uint2*)(f + aoff);
    uint2* stage_c = (uint2*)(f + xoff);
    float* a_s   = f + o; o += (size_t)N*4;
    float* a_d   = f + o; o += (size_t)N*4;
    float* mxs   = f + o; o += 32;          // 3 layer slots x 8 + pad
    float* dinv  = f + o; o += ((size_t)N + 15) & ~15ull;
    int* bcnt    = (int*)(f + o); o += 512;
    int* bptr_r  = (int*)(f + o); o += 512;
    int* bptr_c  = (int*)(f + o); o += 512;
    int* bcur_r  = (int*)(f + o); o += 512;
    int* bcur_c  = (int*)(f + o); o += 512;
    int* ptr_r   = (int*)(f + o); o += ((size_t)N + 16) & ~15ull;
    int* ptr_c   = (int*)(f + o); o += ((size_t)N + 16) & ~15ull;
    int* re_col  = (int*)(f + o); o += (size_t)E;
    int* ce_row  = (int*)(f + o); o += (size_t)E;
    float* b2c   = f + o; o += 3*64;
    _Float16* Bfrag = (_Float16*)(f + o); o += 3*4096;   // 3*8192 fp16
    _Float16* Bg    = (_Float16*)(f + o); o += 3*2560;   // 3*5120 fp16 (5 t-tiles)

    const float* emb_W   = P + 0;
    const float* emb_b   = P + 4096;
    const float* e8_W    = P + 4160;
    const float* gat_W   = P + 16448;
    const float* att_src = P + 28736;
    const float* att_dst = P + 28928;
    const float* gat_b   = P + 29120;
    const float* fus_W   = P + 29312;
    const float* fus_b   = P + 53888;
    const float* ln_g    = P + 54080;
    const float* ln_b    = P + 54272;
    const float* r_W1    = P + 54464;
    const float* r_b1    = P + 56512;
    const float* r_W2    = P + 56544;
    const float* r_b2    = P + 56576;

    hipMemsetAsync(bcnt, 0, 512*sizeof(int), stream);
    k_init<<<CONV_BLKS + 256, 256, 0, stream>>>(
        d_in[2],d_in[3],d_in[4],d_in[5],d_in[6],d_in[7],d_in[8],d_in[9],
        d_in[10],d_in[11],d_in[12],d_in[13],d_in[14],d_in[15],d_in[16],
        d_in[0], row, col, E, NBK, flags, P, bcnt, (unsigned*)mxs);

    int prwblk = (PRW_B2 + 255) / 256;
    kb_scanprew<<<2 + prwblk, 256, 0, stream>>>(bcnt, bptr_r, bptr_c, bcur_r, bcur_c,
                                                NBK, E, fus_W, e8_W, gat_b, fus_b,
                                                gat_W, att_src, att_dst, Bfrag, b2c, Bg);
    kb_bin<<<512, 1024, 0, stream>>>(row, col, bcur_r, bcur_c, stage_r, stage_c, NBK, E);
    kb_place<<<2*NBK, 1024, 0, stream>>>(stage_r, stage_c, bptr_r, bptr_c,
                                         ptr_r, ptr_c, re_col, ce_row, dinv, NBK, N, E);

    int tiles = (N + 15) / 16;
    int fgrid = (tiles + 7) / 8;
    int ggrid = (N + 31) / 32;
    k_embed_g<<<fgrid, 256, 0, stream>>>(xs, flags, emb_W, emb_b, dinv, Bg,
                                         h16, ht16, G16, a_s, a_d, mxs, N);
    for (int i = 0; i < 3; i++){
        k_gather<<<ggrid, 256, 0, stream>>>(ht16, G16, a_s, a_d, mxs + i*8, dinv,
                                            ptr_r, re_col, ptr_c, ce_row,
                                            Aj16, xg16, N);
        if (i < 2){
            k_fuse_g<<<fgrid, 256, 0, stream>>>(Aj16, xg16, dinv, h16, ht16,
                                                Bfrag + (size_t)i*8192, b2c + i*64,
                                                ln_g + i*64, ln_b + i*64,
                                                Bg + (size_t)(i+1)*5120, G16,
                                                a_s, a_d, mxs + (i+1)*8, N);
        } else {
            k_fuse_ro<<<fgrid, 256, 0, stream>>>(Aj16, xg16, h16,
                                                 Bfrag + (size_t)i*8192, b2c + i*64,
                                                 ln_g + i*64, ln_b + i*64,
                                                 r_W1, r_b1, r_W2, r_b2,
                                                 (float*)d_out, N);
        }
    }
}